// Round 11
// baseline (499.211 us; speedup 1.0000x reference)
//
#include <hip/hip_runtime.h>

// ---------------------------------------------------------------------------
// Bidirectional Mamba block, MI355X. Round 10: kconv3 per-thread tile 4->16.
// R9 kconv3: 12FMA:9mem issue mix, 42% VALU, 108us (floor ~23us). New:
// block=(t, 4 h-rows), 256thr = 64co x 4h, 16 w-outputs/thread, ci staged in
// 2 LDS chunks of 32 (41.5KB). Weight reuse x4, FMA:mem ~2.3:1.
// Everything else identical to passing R9. Total 476us; predict ~400us.
// Shapes: B=4, C=64, D=128, L=4096 (l = h*256 + w*16 + t), N=16, R=8.
// ---------------------------------------------------------------------------

#define NL 4096

__device__ __forceinline__ float siluf_(float x) { return x / (1.f + __expf(-x)); }
__device__ __forceinline__ float softplusf_(float x) {
  return (x > 20.f) ? x : log1pf(__expf(x));
}

// Per-b slab offsets (fp32 elements)
#define OXZ  0u          // xz   [256][4096]
#define OUCF 1048576u    // ucf  [128][4096]
#define OUCB 1572864u    // ucb  [128][4096]  (flipped coords)
#define ODLF 2424832u    // dlf  [128][4096]
#define ODLB 2949120u    // dlb  [128][4096]  (flipped coords)
#define OYF  3473408u    // yf   [128][4096]
#define OYB  3997696u    // yb   [128][4096]  (flipped coords)
#define OO   4521984u    // scan scratch: P [262144] S [262144]; later o [128][4096]
#define OO2  5046272u    // bct [2][4096][32] until kscanC; then o2 [4096][64]
#define OX4  5308416u    // x4   [64][4096]   conv3d + residual
#define PER_B 5570560u

#define NCH 64   // scan chunks
#define CL  64   // chunk length

// 1. xz[e,l] = sum_c in_proj_w[e,c] * seq[c,l].  Block=(bi,h,w): LDS stages
// the 64c x 16t column; thread e accumulates 16 t's and stores one full line.
__global__ __launch_bounds__(256) void kxz(
    const float* __restrict__ x, const float* __restrict__ wip,
    float* __restrict__ ws, int b0) {
  int bi = blockIdx.y, gb = b0 + bi;
  float* s = ws + (size_t)bi * PER_B;
  int bid = blockIdx.x;
  int h = bid >> 4, w = bid & 15;
  int tid = threadIdx.x;
  __shared__ float xs[64][16];
  for (int i = tid; i < 1024; i += 256) {
    int c = i >> 4, t = i & 15;
    xs[c][t] = x[(size_t)(gb * 64 + c) * NL + t * 256 + h * 16 + w];
  }
  __syncthreads();
  int e = tid;
  float acc[16];
#pragma unroll
  for (int t = 0; t < 16; ++t) acc[t] = 0.f;
  for (int c = 0; c < 64; ++c) {
    float wv = wip[e * 64 + c];
#pragma unroll
    for (int t = 0; t < 16; ++t) acc[t] = fmaf(wv, xs[c][t], acc[t]);
  }
  float4* dst = (float4*)(s + OXZ + (size_t)e * NL + h * 256 + w * 16);
#pragma unroll
  for (int q = 0; q < 4; ++q)
    dst[q] = make_float4(acc[q * 4], acc[q * 4 + 1], acc[q * 4 + 2], acc[q * 4 + 3]);
}

// 2. Fused prep per (bi, 32-l tile): dwconv+silu (fwd tile lt; bwd flipped
// tile 127-lt via mirror identity, same X tile), x_dbl = xproj@uc,
// delta = softplus(dtw@dt + dtb), bct (B/C, [l][32]). All writes coalesced.
__global__ __launch_bounds__(256) void k2prep(
    const float* __restrict__ cwf, const float* __restrict__ cbf,
    const float* __restrict__ xpf, const float* __restrict__ dtwf,
    const float* __restrict__ dtbf,
    const float* __restrict__ cwb, const float* __restrict__ cbb,
    const float* __restrict__ xpb, const float* __restrict__ dtwb,
    const float* __restrict__ dtbb,
    float* __restrict__ ws) {
  int bi = blockIdx.y;
  float* s = ws + (size_t)bi * PER_B;
  int lt = blockIdx.x;           // fwd tile index
  int l0 = lt * 32;              // fwd tile start (original coords)
  int l0b = (127 - lt) * 32;     // bwd tile start (flipped coords)
  int tid = threadIdx.x;

  __shared__ float X[128][40];       // j=0..37 <-> xz[l0-3 .. l0+34]
  __shared__ float ucs[2][128][32];
  __shared__ float xds[2][40][33];

  for (int i = tid; i < 128 * 38; i += 256) {
    int d = i / 38, j = i - d * 38;
    int l = l0 - 3 + j;
    X[d][j] = (l >= 0 && l < NL) ? s[OXZ + (size_t)d * NL + l] : 0.f;
  }
  __syncthreads();

  // dwconv + silu.
  for (int i = tid; i < 2 * 128 * 32; i += 256) {
    int br = i >> 12, rem = i & 4095;
    int d = rem >> 5, li = rem & 31;
    float a;
    if (br == 0) {
      a = cbf[d];
#pragma unroll
      for (int k = 0; k < 4; ++k) a = fmaf(cwf[d * 4 + k], X[d][li + k], a);
    } else {
      a = cbb[d];
#pragma unroll
      for (int k = 0; k < 4; ++k) a = fmaf(cwb[d * 4 + k], X[d][37 - li - k], a);
    }
    a = siluf_(a);
    ucs[br][d][li] = a;
    int lg = br ? (l0b + li) : (l0 + li);
    s[(br ? OUCB : OUCF) + (size_t)d * NL + lg] = a;
  }
  __syncthreads();

  // x_dbl[br][e][li] = sum_d xproj[e,d] * ucs[br][d][li]
  for (int j = 0; j < 10; ++j) {
    int out = j * 256 + tid;
    int br = out / 1280;
    int rem = out - br * 1280;
    int e = rem >> 5, li = rem & 31;
    const float* xp = br ? xpb : xpf;
    float acc = 0.f;
    for (int d = 0; d < 128; ++d)
      acc = fmaf(xp[e * 128 + d], ucs[br][d][li], acc);
    xds[br][e][li] = acc;
  }
  __syncthreads();

  // delta
  for (int i = tid; i < 2 * 128 * 32; i += 256) {
    int br = i >> 12, rem = i & 4095;
    int d = rem >> 5, li = rem & 31;
    const float* dtw = br ? dtwb : dtwf;
    float pre = (br ? dtbb : dtbf)[d];
#pragma unroll
    for (int r = 0; r < 8; ++r)
      pre = fmaf(dtw[d * 8 + r], xds[br][r][li], pre);
    int lg = br ? (l0b + li) : (l0 + li);
    s[(br ? ODLB : ODLF) + (size_t)d * NL + lg] = softplusf_(pre);
  }
  // bct[(dir*4096 + l)*32 + k] = xds[dir][8+k][li]  (contiguous runs)
  for (int i = tid; i < 2 * 32 * 32; i += 256) {
    int dir = i >> 10;
    int li = (i >> 5) & 31, k = i & 31;
    int lg = dir ? (l0b + li) : (l0 + li);
    s[OO2 + ((size_t)dir * 4096 + lg) * 32 + k] = xds[dir][8 + k][li];
  }
}

// 5a. Phase A: per-chunk local scan. P = prod(dA), S = chunk scan (h0=0).
__global__ __launch_bounds__(64) void kscanA(
    const float* __restrict__ Alf, const float* __restrict__ Alb,
    float* __restrict__ ws) {
  int bi = blockIdx.y;
  float* s = ws + (size_t)bi * PER_B;
  int xid = blockIdx.x;
  int chunk = xid >> 6, dir = (xid >> 5) & 1, dblk = xid & 31;
  int n = threadIdx.x & 15, g = threadIdx.x >> 4;
  int d = dblk * 4 + g;
  const float* uc = s + (dir ? OUCB : OUCF) + (size_t)d * NL;
  const float* dl = s + (dir ? ODLB : ODLF) + (size_t)d * NL;
  const float* bct = s + OO2 + (size_t)dir * 4096 * 32;
  float A = -__expf((dir ? Alb : Alf)[d * 16 + n]);
  int l0 = chunk * CL;
  float P = 1.f, S = 0.f;
#pragma unroll 4
  for (int i = 0; i < CL; ++i) {
    int l = l0 + i;
    float dv = dl[l];
    float dA = __expf(dv * A);
    S = fmaf(dA, S, dv * bct[(size_t)l * 32 + n] * uc[l]);
    P *= dA;
  }
  size_t cidx = ((size_t)(chunk * 2 + dir) * 128 + d) * 16 + n;
  s[OO + cidx] = P;
  s[OO + 262144u + cidx] = S;
}

// 5b. Phase B: carry combine. S[c] <- h_in (state at chunk start).
__global__ __launch_bounds__(64) void kscanB(float* __restrict__ ws) {
  int bi = blockIdx.y;
  float* s = ws + (size_t)bi * PER_B;
  int dir = blockIdx.x >> 5, dblk = blockIdx.x & 31;
  int tid = threadIdx.x;
  size_t base = (size_t)dir * 2048 + dblk * 64 + tid;
  float carry = 0.f;
#pragma unroll 4
  for (int c = 0; c < NCH; ++c) {
    size_t idx = (size_t)c * 4096 + base;
    float pv = s[OO + idx], sv = s[OO + 262144u + idx];
    s[OO + 262144u + idx] = carry;
    carry = fmaf(pv, carry, sv);
  }
}

// 5c. Phase C: seeded re-scan; y staged in LDS, coalesced full-line stores.
__global__ __launch_bounds__(64) void kscanC(
    const float* __restrict__ Alf, const float* __restrict__ Df,
    const float* __restrict__ Alb, const float* __restrict__ Db,
    float* __restrict__ ws) {
  int bi = blockIdx.y;
  float* s = ws + (size_t)bi * PER_B;
  int xid = blockIdx.x;
  int chunk = xid >> 6, dir = (xid >> 5) & 1, dblk = xid & 31;
  int tid = threadIdx.x;
  int n = tid & 15, g = tid >> 4;
  int d = dblk * 4 + g;
  const float* uc = s + (dir ? OUCB : OUCF) + (size_t)d * NL;
  const float* dl = s + (dir ? ODLB : ODLF) + (size_t)d * NL;
  const float* bct = s + OO2 + (size_t)dir * 4096 * 32;
  float* ybase = s + (dir ? OYB : OYF);
  float A = -__expf((dir ? Alb : Alf)[d * 16 + n]);
  float Dv = (dir ? Db : Df)[d];
  size_t cidx = ((size_t)(chunk * 2 + dir) * 128 + d) * 16 + n;
  float h = s[OO + 262144u + cidx];  // h_in at chunk start
  int l0 = chunk * CL;
  __shared__ float ps[4][CL];
#pragma unroll 2
  for (int i = 0; i < CL; ++i) {
    int l = l0 + i;
    float dv = dl[l], uv = uc[l];
    float dA = __expf(dv * A);
    h = fmaf(dA, h, dv * bct[(size_t)l * 32 + n] * uv);
    float p = h * bct[(size_t)l * 32 + 16 + n];
    p += __shfl_xor(p, 1, 16);
    p += __shfl_xor(p, 2, 16);
    p += __shfl_xor(p, 4, 16);
    p += __shfl_xor(p, 8, 16);
    if (n == 0) ps[g][i] = fmaf(uv, Dv, p);
  }
#pragma unroll
  for (int dd = 0; dd < 4; ++dd)
    ybase[(size_t)(dblk * 4 + dd) * NL + l0 + tid] = ps[dd][tid];
}

// 6. o[d,l] = (yf[d,l] + yb[d,L-1-l]) * silu(z[l])
__global__ void kgate(float* __restrict__ ws) {
  int bi = blockIdx.y;
  float* s = ws + (size_t)bi * PER_B;
  int idx = blockIdx.x * 256 + threadIdx.x;  // 128*4096
  int d = idx >> 12, l = idx & 4095;
  float gz = siluf_(s[OXZ + (size_t)(128 + d) * NL + l]);
  float v = s[OYF + (size_t)d * NL + l] + s[OYB + (size_t)d * NL + (NL - 1 - l)];
  s[OO + (size_t)d * NL + l] = v * gz;
}

// 7. o2[l,c] = sum_d out_proj_w[c,d] * o[d,l]   (o2 bytes == x_recon NCDHW)
__global__ void kout(const float* __restrict__ wout, float* __restrict__ ws) {
  int bi = blockIdx.y;
  float* s = ws + (size_t)bi * PER_B;
  int idx = blockIdx.x * 256 + threadIdx.x;  // 4096*64
  int l = idx >> 6, c = idx & 63;
  float acc = 0.f;
  for (int d = 0; d < 128; ++d)
    acc = fmaf(wout[c * 128 + d], s[OO + (size_t)d * NL + l], acc);
  s[OO2 + (size_t)l * 64 + c] = acc;
}

// 8. x4 = conv3d(x_recon, proj_w, pad=1) + proj_b + residual x.
// Block = (t, h-quad): 256 thr = 64co x 4h, 16 w-outputs each.
// LDS stages ci in 2 chunks of 32: Xs[32][3][6][18] = 41.5 KB.
__global__ __launch_bounds__(256) void kconv3(
    const float* __restrict__ pw, const float* __restrict__ pb,
    const float* __restrict__ xin, float* __restrict__ ws, int b0) {
  int bi = blockIdx.y, gb = b0 + bi;
  float* s = ws + (size_t)bi * PER_B;
  int t = blockIdx.x >> 2, hq = blockIdx.x & 3;
  int h0 = hq * 4;
  int tid = threadIdx.x;
  int co = tid >> 2, hh = tid & 3;
  int h = h0 + hh;
  const float* xr = s + OO2;  // (L,C) bytes == (C,T,H,W)
  __shared__ float Xs[32][3][6][18];  // ci-chunk x t-halo x h-halo x w-pad
  float acc[16];
#pragma unroll
  for (int w = 0; w < 16; ++w) acc[w] = 0.f;

  for (int chunk = 0; chunk < 2; ++chunk) {
    __syncthreads();
    for (int i = tid; i < 32 * 324; i += 256) {
      int ci = i / 324;
      int rem = i - ci * 324;
      int tt = rem / 108;
      int rem2 = rem - tt * 108;
      int hh2 = rem2 / 18;
      int ww = rem2 - hh2 * 18;
      int ts = t + tt - 1, hs = h0 + hh2 - 1, wv = ww - 1;
      float v = 0.f;
      if (ts >= 0 && ts < 16 && hs >= 0 && hs < 16 && wv >= 0 && wv < 16)
        v = xr[(size_t)(chunk * 32 + ci) * NL + ts * 256 + hs * 16 + wv];
      Xs[ci][tt][hh2][ww] = v;
    }
    __syncthreads();
    const float* wc = pw + (co * 64 + chunk * 32) * 27;
    for (int ci = 0; ci < 32; ++ci) {
#pragma unroll
      for (int kt = 0; kt < 3; ++kt) {
#pragma unroll
        for (int kh = 0; kh < 3; ++kh) {
          const float* wr = wc + ci * 27 + kt * 9 + kh * 3;
          float wv0 = wr[0], wv1 = wr[1], wv2 = wr[2];
          const float* row = &Xs[ci][kt][hh + kh][0];
          float xp = row[0], xc = row[1];
#pragma unroll
          for (int w = 0; w < 16; ++w) {
            float xn = row[w + 2];
            acc[w] = fmaf(wv0, xp, fmaf(wv1, xc, fmaf(wv2, xn, acc[w])));
            xp = xc; xc = xn;
          }
        }
      }
    }
  }
  float bias = pb[co];
  size_t off = (size_t)co * NL + t * 256 + h * 16;
  size_t ibase = (size_t)(gb * 64 + co) * NL + t * 256 + h * 16;
#pragma unroll
  for (int w = 0; w < 16; ++w)
    s[OX4 + off + w] = acc[w] + bias + xin[ibase + w];
}

// 9. out = 1x1x1 channel mix + norm_b -> fp32 output
__global__ void knorm(const float* __restrict__ nw, const float* __restrict__ nb,
                      float* __restrict__ out, float* __restrict__ ws, int b0) {
  int bi = blockIdx.y, gb = b0 + bi;
  float* s = ws + (size_t)bi * PER_B;
  int idx = blockIdx.x * 256 + threadIdx.x;  // 64*4096
  int co = idx >> 12, p = idx & 4095;
  float acc = nb[co];
  for (int ci = 0; ci < 64; ++ci)
    acc = fmaf(nw[co * 64 + ci], s[OX4 + (size_t)ci * NL + p], acc);
  out[(size_t)(gb * 64 + co) * NL + p] = acc;
}

// ---------------------------------------------------------------------------
extern "C" void kernel_launch(void* const* d_in, const int* in_sizes, int n_in,
                              void* d_out, int out_size, void* d_ws, size_t ws_size,
                              hipStream_t stream) {
  const float* x    = (const float*)d_in[0];
  const float* wip  = (const float*)d_in[1];
  const float* cwf  = (const float*)d_in[2];
  const float* cbf  = (const float*)d_in[3];
  const float* xpf  = (const float*)d_in[4];
  const float* dtwf = (const float*)d_in[5];
  const float* dtbf = (const float*)d_in[6];
  const float* Alf  = (const float*)d_in[7];
  const float* Df   = (const float*)d_in[8];
  const float* cwb  = (const float*)d_in[9];
  const float* cbb  = (const float*)d_in[10];
  const float* xpb  = (const float*)d_in[11];
  const float* dtwb = (const float*)d_in[12];
  const float* dtbb = (const float*)d_in[13];
  const float* Alb  = (const float*)d_in[14];
  const float* Db   = (const float*)d_in[15];
  const float* wout = (const float*)d_in[16];
  const float* pw   = (const float*)d_in[17];
  const float* pb   = (const float*)d_in[18];
  const float* nw   = (const float*)d_in[19];
  const float* nb   = (const float*)d_in[20];

  const size_t PER_B_BYTES = (size_t)PER_B * 4;  // 22,282,240 per batch slab
  int bcnt;
  if (ws_size >= 4 * PER_B_BYTES) bcnt = 4;
  else if (ws_size >= PER_B_BYTES) bcnt = 1;
  else return;
  int passes = 4 / bcnt;

  float* ws = (float*)d_ws;
  for (int p = 0; p < passes; ++p) {
    int b0 = p * bcnt;
    kxz   <<<dim3(256, bcnt), 256, 0, stream>>>(x, wip, ws, b0);
    k2prep<<<dim3(128, bcnt), 256, 0, stream>>>(cwf, cbf, xpf, dtwf, dtbf,
                                                cwb, cbb, xpb, dtwb, dtbb, ws);
    kscanA<<<dim3(4096, bcnt), 64, 0, stream>>>(Alf, Alb, ws);
    kscanB<<<dim3(64, bcnt), 64, 0, stream>>>(ws);
    kscanC<<<dim3(4096, bcnt), 64, 0, stream>>>(Alf, Df, Alb, Db, ws);
    kgate <<<dim3(2048, bcnt), 256, 0, stream>>>(ws);
    kout  <<<dim3(1024, bcnt), 256, 0, stream>>>(wout, ws);
    kconv3<<<dim3(64, bcnt), 256, 0, stream>>>(pw, pb, x, ws, b0);
    knorm <<<dim3(1024, bcnt), 256, 0, stream>>>(nw, nb, (float*)d_out, ws, b0);
  }
}

// Round 12
// 460.873 us; speedup vs baseline: 1.0832x; 1.0832x over previous
//
#include <hip/hip_runtime.h>

// ---------------------------------------------------------------------------
// Bidirectional Mamba block, MI355X. Round 11: kconv3 ci-split grid.
// R10 regressed (129us): 16-w tiles were right but grid shrank to 1 block/CU
// (occ 10.9%, VALU 29%) -> TLP starvation. Now grid = (t, hq, ci-half) =
// 512 blocks (2/CU); each block computes a 32-ci partial sum; half 0 writes
// partial to dead OYF region (OX4B), half 1 adds bias+residual into OX4;
// knorm sums both partials. Everything else = passing R9/R10 pipeline.
// Shapes: B=4, C=64, D=128, L=4096 (l = h*256 + w*16 + t), N=16, R=8.
// ---------------------------------------------------------------------------

#define NL 4096

__device__ __forceinline__ float siluf_(float x) { return x / (1.f + __expf(-x)); }
__device__ __forceinline__ float softplusf_(float x) {
  return (x > 20.f) ? x : log1pf(__expf(x));
}

// Per-b slab offsets (fp32 elements)
#define OXZ  0u          // xz   [256][4096]
#define OUCF 1048576u    // ucf  [128][4096]
#define OUCB 1572864u    // ucb  [128][4096]  (flipped coords)
#define ODLF 2424832u    // dlf  [128][4096]
#define ODLB 2949120u    // dlb  [128][4096]  (flipped coords)
#define OYF  3473408u    // yf   [128][4096]; after kgate: OX4B (conv3 partial)
#define OYB  3997696u    // yb   [128][4096]  (flipped coords)
#define OO   4521984u    // scan scratch: P [262144] S [262144]; later o [128][4096]
#define OO2  5046272u    // bct [2][4096][32] until kscanC; then o2 [4096][64]
#define OX4  5308416u    // x4   [64][4096]   conv3d + residual (ci-half-1 part)
#define OX4B 3473408u    // conv3d ci-half-0 partial (over dead yf)
#define PER_B 5570560u

#define NCH 64   // scan chunks
#define CL  64   // chunk length

// 1. xz[e,l] = sum_c in_proj_w[e,c] * seq[c,l].  Block=(bi,h,w): LDS stages
// the 64c x 16t column; thread e accumulates 16 t's and stores one full line.
__global__ __launch_bounds__(256) void kxz(
    const float* __restrict__ x, const float* __restrict__ wip,
    float* __restrict__ ws, int b0) {
  int bi = blockIdx.y, gb = b0 + bi;
  float* s = ws + (size_t)bi * PER_B;
  int bid = blockIdx.x;
  int h = bid >> 4, w = bid & 15;
  int tid = threadIdx.x;
  __shared__ float xs[64][16];
  for (int i = tid; i < 1024; i += 256) {
    int c = i >> 4, t = i & 15;
    xs[c][t] = x[(size_t)(gb * 64 + c) * NL + t * 256 + h * 16 + w];
  }
  __syncthreads();
  int e = tid;
  float acc[16];
#pragma unroll
  for (int t = 0; t < 16; ++t) acc[t] = 0.f;
  for (int c = 0; c < 64; ++c) {
    float wv = wip[e * 64 + c];
#pragma unroll
    for (int t = 0; t < 16; ++t) acc[t] = fmaf(wv, xs[c][t], acc[t]);
  }
  float4* dst = (float4*)(s + OXZ + (size_t)e * NL + h * 256 + w * 16);
#pragma unroll
  for (int q = 0; q < 4; ++q)
    dst[q] = make_float4(acc[q * 4], acc[q * 4 + 1], acc[q * 4 + 2], acc[q * 4 + 3]);
}

// 2. Fused prep per (bi, 32-l tile): dwconv+silu (fwd tile lt; bwd flipped
// tile 127-lt via mirror identity, same X tile), x_dbl = xproj@uc,
// delta = softplus(dtw@dt + dtb), bct (B/C, [l][32]). All writes coalesced.
__global__ __launch_bounds__(256) void k2prep(
    const float* __restrict__ cwf, const float* __restrict__ cbf,
    const float* __restrict__ xpf, const float* __restrict__ dtwf,
    const float* __restrict__ dtbf,
    const float* __restrict__ cwb, const float* __restrict__ cbb,
    const float* __restrict__ xpb, const float* __restrict__ dtwb,
    const float* __restrict__ dtbb,
    float* __restrict__ ws) {
  int bi = blockIdx.y;
  float* s = ws + (size_t)bi * PER_B;
  int lt = blockIdx.x;           // fwd tile index
  int l0 = lt * 32;              // fwd tile start (original coords)
  int l0b = (127 - lt) * 32;     // bwd tile start (flipped coords)
  int tid = threadIdx.x;

  __shared__ float X[128][40];       // j=0..37 <-> xz[l0-3 .. l0+34]
  __shared__ float ucs[2][128][32];
  __shared__ float xds[2][40][33];

  for (int i = tid; i < 128 * 38; i += 256) {
    int d = i / 38, j = i - d * 38;
    int l = l0 - 3 + j;
    X[d][j] = (l >= 0 && l < NL) ? s[OXZ + (size_t)d * NL + l] : 0.f;
  }
  __syncthreads();

  // dwconv + silu.
  for (int i = tid; i < 2 * 128 * 32; i += 256) {
    int br = i >> 12, rem = i & 4095;
    int d = rem >> 5, li = rem & 31;
    float a;
    if (br == 0) {
      a = cbf[d];
#pragma unroll
      for (int k = 0; k < 4; ++k) a = fmaf(cwf[d * 4 + k], X[d][li + k], a);
    } else {
      a = cbb[d];
#pragma unroll
      for (int k = 0; k < 4; ++k) a = fmaf(cwb[d * 4 + k], X[d][37 - li - k], a);
    }
    a = siluf_(a);
    ucs[br][d][li] = a;
    int lg = br ? (l0b + li) : (l0 + li);
    s[(br ? OUCB : OUCF) + (size_t)d * NL + lg] = a;
  }
  __syncthreads();

  // x_dbl[br][e][li] = sum_d xproj[e,d] * ucs[br][d][li]
  for (int j = 0; j < 10; ++j) {
    int out = j * 256 + tid;
    int br = out / 1280;
    int rem = out - br * 1280;
    int e = rem >> 5, li = rem & 31;
    const float* xp = br ? xpb : xpf;
    float acc = 0.f;
    for (int d = 0; d < 128; ++d)
      acc = fmaf(xp[e * 128 + d], ucs[br][d][li], acc);
    xds[br][e][li] = acc;
  }
  __syncthreads();

  // delta
  for (int i = tid; i < 2 * 128 * 32; i += 256) {
    int br = i >> 12, rem = i & 4095;
    int d = rem >> 5, li = rem & 31;
    const float* dtw = br ? dtwb : dtwf;
    float pre = (br ? dtbb : dtbf)[d];
#pragma unroll
    for (int r = 0; r < 8; ++r)
      pre = fmaf(dtw[d * 8 + r], xds[br][r][li], pre);
    int lg = br ? (l0b + li) : (l0 + li);
    s[(br ? ODLB : ODLF) + (size_t)d * NL + lg] = softplusf_(pre);
  }
  // bct[(dir*4096 + l)*32 + k] = xds[dir][8+k][li]  (contiguous runs)
  for (int i = tid; i < 2 * 32 * 32; i += 256) {
    int dir = i >> 10;
    int li = (i >> 5) & 31, k = i & 31;
    int lg = dir ? (l0b + li) : (l0 + li);
    s[OO2 + ((size_t)dir * 4096 + lg) * 32 + k] = xds[dir][8 + k][li];
  }
}

// 5a. Phase A: per-chunk local scan. P = prod(dA), S = chunk scan (h0=0).
__global__ __launch_bounds__(64) void kscanA(
    const float* __restrict__ Alf, const float* __restrict__ Alb,
    float* __restrict__ ws) {
  int bi = blockIdx.y;
  float* s = ws + (size_t)bi * PER_B;
  int xid = blockIdx.x;
  int chunk = xid >> 6, dir = (xid >> 5) & 1, dblk = xid & 31;
  int n = threadIdx.x & 15, g = threadIdx.x >> 4;
  int d = dblk * 4 + g;
  const float* uc = s + (dir ? OUCB : OUCF) + (size_t)d * NL;
  const float* dl = s + (dir ? ODLB : ODLF) + (size_t)d * NL;
  const float* bct = s + OO2 + (size_t)dir * 4096 * 32;
  float A = -__expf((dir ? Alb : Alf)[d * 16 + n]);
  int l0 = chunk * CL;
  float P = 1.f, S = 0.f;
#pragma unroll 4
  for (int i = 0; i < CL; ++i) {
    int l = l0 + i;
    float dv = dl[l];
    float dA = __expf(dv * A);
    S = fmaf(dA, S, dv * bct[(size_t)l * 32 + n] * uc[l]);
    P *= dA;
  }
  size_t cidx = ((size_t)(chunk * 2 + dir) * 128 + d) * 16 + n;
  s[OO + cidx] = P;
  s[OO + 262144u + cidx] = S;
}

// 5b. Phase B: carry combine. S[c] <- h_in (state at chunk start).
__global__ __launch_bounds__(64) void kscanB(float* __restrict__ ws) {
  int bi = blockIdx.y;
  float* s = ws + (size_t)bi * PER_B;
  int dir = blockIdx.x >> 5, dblk = blockIdx.x & 31;
  int tid = threadIdx.x;
  size_t base = (size_t)dir * 2048 + dblk * 64 + tid;
  float carry = 0.f;
#pragma unroll 4
  for (int c = 0; c < NCH; ++c) {
    size_t idx = (size_t)c * 4096 + base;
    float pv = s[OO + idx], sv = s[OO + 262144u + idx];
    s[OO + 262144u + idx] = carry;
    carry = fmaf(pv, carry, sv);
  }
}

// 5c. Phase C: seeded re-scan; y staged in LDS, coalesced full-line stores.
__global__ __launch_bounds__(64) void kscanC(
    const float* __restrict__ Alf, const float* __restrict__ Df,
    const float* __restrict__ Alb, const float* __restrict__ Db,
    float* __restrict__ ws) {
  int bi = blockIdx.y;
  float* s = ws + (size_t)bi * PER_B;
  int xid = blockIdx.x;
  int chunk = xid >> 6, dir = (xid >> 5) & 1, dblk = xid & 31;
  int tid = threadIdx.x;
  int n = tid & 15, g = tid >> 4;
  int d = dblk * 4 + g;
  const float* uc = s + (dir ? OUCB : OUCF) + (size_t)d * NL;
  const float* dl = s + (dir ? ODLB : ODLF) + (size_t)d * NL;
  const float* bct = s + OO2 + (size_t)dir * 4096 * 32;
  float* ybase = s + (dir ? OYB : OYF);
  float A = -__expf((dir ? Alb : Alf)[d * 16 + n]);
  float Dv = (dir ? Db : Df)[d];
  size_t cidx = ((size_t)(chunk * 2 + dir) * 128 + d) * 16 + n;
  float h = s[OO + 262144u + cidx];  // h_in at chunk start
  int l0 = chunk * CL;
  __shared__ float ps[4][CL];
#pragma unroll 2
  for (int i = 0; i < CL; ++i) {
    int l = l0 + i;
    float dv = dl[l], uv = uc[l];
    float dA = __expf(dv * A);
    h = fmaf(dA, h, dv * bct[(size_t)l * 32 + n] * uv);
    float p = h * bct[(size_t)l * 32 + 16 + n];
    p += __shfl_xor(p, 1, 16);
    p += __shfl_xor(p, 2, 16);
    p += __shfl_xor(p, 4, 16);
    p += __shfl_xor(p, 8, 16);
    if (n == 0) ps[g][i] = fmaf(uv, Dv, p);
  }
#pragma unroll
  for (int dd = 0; dd < 4; ++dd)
    ybase[(size_t)(dblk * 4 + dd) * NL + l0 + tid] = ps[dd][tid];
}

// 6. o[d,l] = (yf[d,l] + yb[d,L-1-l]) * silu(z[l])
__global__ void kgate(float* __restrict__ ws) {
  int bi = blockIdx.y;
  float* s = ws + (size_t)bi * PER_B;
  int idx = blockIdx.x * 256 + threadIdx.x;  // 128*4096
  int d = idx >> 12, l = idx & 4095;
  float gz = siluf_(s[OXZ + (size_t)(128 + d) * NL + l]);
  float v = s[OYF + (size_t)d * NL + l] + s[OYB + (size_t)d * NL + (NL - 1 - l)];
  s[OO + (size_t)d * NL + l] = v * gz;
}

// 7. o2[l,c] = sum_d out_proj_w[c,d] * o[d,l]   (o2 bytes == x_recon NCDHW)
__global__ void kout(const float* __restrict__ wout, float* __restrict__ ws) {
  int bi = blockIdx.y;
  float* s = ws + (size_t)bi * PER_B;
  int idx = blockIdx.x * 256 + threadIdx.x;  // 4096*64
  int l = idx >> 6, c = idx & 63;
  float acc = 0.f;
  for (int d = 0; d < 128; ++d)
    acc = fmaf(wout[c * 128 + d], s[OO + (size_t)d * NL + l], acc);
  s[OO2 + (size_t)l * 64 + c] = acc;
}

// 8. x4 = conv3d(x_recon, proj_w, pad=1) + proj_b + residual x.
// Grid = (t, hq, ci-half): 128 blocks/slab (2 blocks/CU). 256 thr = 64co x 4h,
// 16 w-outputs each over its 32-ci half. Xs[32][3][6][18] = 41.5 KB.
// ci-half 0 -> partial to OX4B; ci-half 1 -> + bias + residual to OX4.
__global__ __launch_bounds__(256) void kconv3(
    const float* __restrict__ pw, const float* __restrict__ pb,
    const float* __restrict__ xin, float* __restrict__ ws, int b0) {
  int bi = blockIdx.y, gb = b0 + bi;
  float* s = ws + (size_t)bi * PER_B;
  int t = blockIdx.x >> 3, hq = (blockIdx.x >> 1) & 3, cih = blockIdx.x & 1;
  int h0 = hq * 4;
  int tid = threadIdx.x;
  int co = tid >> 2, hh = tid & 3;
  int h = h0 + hh;
  const float* xr = s + OO2;  // (L,C) bytes == (C,T,H,W)
  __shared__ float Xs[32][3][6][18];
  float acc[16];
#pragma unroll
  for (int w = 0; w < 16; ++w) acc[w] = 0.f;

  for (int i = tid; i < 32 * 324; i += 256) {
    int ci = i / 324;
    int rem = i - ci * 324;
    int tt = rem / 108;
    int rem2 = rem - tt * 108;
    int hh2 = rem2 / 18;
    int ww = rem2 - hh2 * 18;
    int ts = t + tt - 1, hs = h0 + hh2 - 1, wv = ww - 1;
    float v = 0.f;
    if (ts >= 0 && ts < 16 && hs >= 0 && hs < 16 && wv >= 0 && wv < 16)
      v = xr[(size_t)(cih * 32 + ci) * NL + ts * 256 + hs * 16 + wv];
    Xs[ci][tt][hh2][ww] = v;
  }
  __syncthreads();
  const float* wc = pw + (co * 64 + cih * 32) * 27;
  for (int ci = 0; ci < 32; ++ci) {
#pragma unroll
    for (int kt = 0; kt < 3; ++kt) {
#pragma unroll
      for (int kh = 0; kh < 3; ++kh) {
        const float* wr = wc + ci * 27 + kt * 9 + kh * 3;
        float wv0 = wr[0], wv1 = wr[1], wv2 = wr[2];
        const float* row = &Xs[ci][kt][hh + kh][0];
        float xp = row[0], xc = row[1];
#pragma unroll
        for (int w = 0; w < 16; ++w) {
          float xn = row[w + 2];
          acc[w] = fmaf(wv0, xp, fmaf(wv1, xc, fmaf(wv2, xn, acc[w])));
          xp = xc; xc = xn;
        }
      }
    }
  }
  size_t off = (size_t)co * NL + t * 256 + h * 16;
  if (cih == 1) {
    float bias = pb[co];
    size_t ibase = (size_t)(gb * 64 + co) * NL + t * 256 + h * 16;
#pragma unroll
    for (int w = 0; w < 16; ++w)
      s[OX4 + off + w] = acc[w] + bias + xin[ibase + w];
  } else {
#pragma unroll
    for (int w = 0; w < 16; ++w)
      s[OX4B + off + w] = acc[w];
  }
}

// 9. out = 1x1x1 channel mix + norm_b -> fp32 output. Sums the two conv3
// partials (OX4 has bias+residual; OX4B is the ci-half-0 partial).
__global__ void knorm(const float* __restrict__ nw, const float* __restrict__ nb,
                      float* __restrict__ out, float* __restrict__ ws, int b0) {
  int bi = blockIdx.y, gb = b0 + bi;
  float* s = ws + (size_t)bi * PER_B;
  int idx = blockIdx.x * 256 + threadIdx.x;  // 64*4096
  int co = idx >> 12, p = idx & 4095;
  float acc = nb[co];
  for (int ci = 0; ci < 64; ++ci) {
    float xv = s[OX4 + (size_t)ci * NL + p] + s[OX4B + (size_t)ci * NL + p];
    acc = fmaf(nw[co * 64 + ci], xv, acc);
  }
  out[(size_t)(gb * 64 + co) * NL + p] = acc;
}

// ---------------------------------------------------------------------------
extern "C" void kernel_launch(void* const* d_in, const int* in_sizes, int n_in,
                              void* d_out, int out_size, void* d_ws, size_t ws_size,
                              hipStream_t stream) {
  const float* x    = (const float*)d_in[0];
  const float* wip  = (const float*)d_in[1];
  const float* cwf  = (const float*)d_in[2];
  const float* cbf  = (const float*)d_in[3];
  const float* xpf  = (const float*)d_in[4];
  const float* dtwf = (const float*)d_in[5];
  const float* dtbf = (const float*)d_in[6];
  const float* Alf  = (const float*)d_in[7];
  const float* Df   = (const float*)d_in[8];
  const float* cwb  = (const float*)d_in[9];
  const float* cbb  = (const float*)d_in[10];
  const float* xpb  = (const float*)d_in[11];
  const float* dtwb = (const float*)d_in[12];
  const float* dtbb = (const float*)d_in[13];
  const float* Alb  = (const float*)d_in[14];
  const float* Db   = (const float*)d_in[15];
  const float* wout = (const float*)d_in[16];
  const float* pw   = (const float*)d_in[17];
  const float* pb   = (const float*)d_in[18];
  const float* nw   = (const float*)d_in[19];
  const float* nb   = (const float*)d_in[20];

  const size_t PER_B_BYTES = (size_t)PER_B * 4;  // 22,282,240 per batch slab
  int bcnt;
  if (ws_size >= 4 * PER_B_BYTES) bcnt = 4;
  else if (ws_size >= PER_B_BYTES) bcnt = 1;
  else return;
  int passes = 4 / bcnt;

  float* ws = (float*)d_ws;
  for (int p = 0; p < passes; ++p) {
    int b0 = p * bcnt;
    kxz   <<<dim3(256, bcnt), 256, 0, stream>>>(x, wip, ws, b0);
    k2prep<<<dim3(128, bcnt), 256, 0, stream>>>(cwf, cbf, xpf, dtwf, dtbf,
                                                cwb, cbb, xpb, dtwb, dtbb, ws);
    kscanA<<<dim3(4096, bcnt), 64, 0, stream>>>(Alf, Alb, ws);
    kscanB<<<dim3(64, bcnt), 64, 0, stream>>>(ws);
    kscanC<<<dim3(4096, bcnt), 64, 0, stream>>>(Alf, Df, Alb, Db, ws);
    kgate <<<dim3(2048, bcnt), 256, 0, stream>>>(ws);
    kout  <<<dim3(1024, bcnt), 256, 0, stream>>>(wout, ws);
    kconv3<<<dim3(128, bcnt), 256, 0, stream>>>(pw, pb, x, ws, b0);
    knorm <<<dim3(1024, bcnt), 256, 0, stream>>>(nw, nb, (float*)d_out, ws, b0);
  }
}

// Round 13
// 373.132 us; speedup vs baseline: 1.3379x; 1.2351x over previous
//
#include <hip/hip_runtime.h>

// ---------------------------------------------------------------------------
// Bidirectional Mamba block, MI355X. Round 12:
//  - kconv3 ci-quarters: 1024 blocks (4/CU), partials in 4 dead 1MB regions
//  - kgate fused into kout (LDS ot tile; matmul from LDS; transposed store)
//  - knorm LDS-tiled (stages 4-partial sum once, 16 outputs/thread)
// Shapes: B=4, C=64, D=128, L=4096 (l = h*256 + w*16 + t), N=16, R=8.
// ---------------------------------------------------------------------------

#define NL 4096

__device__ __forceinline__ float siluf_(float x) { return x / (1.f + __expf(-x)); }
__device__ __forceinline__ float softplusf_(float x) {
  return (x > 20.f) ? x : log1pf(__expf(x));
}

// Per-b slab offsets (fp32 elements)
#define OXZ  0u          // xz [256][4096]; rows0-63/64-127 become conv3 partials q0/q1
#define OUCF 1048576u    // ucf  [128][4096]
#define OUCB 1572864u    // ucb  [128][4096]  (flipped coords)
#define ODLF 2424832u    // dlf  [128][4096]
#define ODLB 2949120u    // dlb  [128][4096]  (flipped coords)
#define OYF  3473408u    // yf [128][4096]; first half becomes conv3 partial q2 (OX4B)
#define OYB  3997696u    // yb   [128][4096]  (flipped coords)
#define OO   4521984u    // scan scratch: P [262144] S [262144]
#define OO2  5046272u    // bct [2][4096][32] until kscanC; then o2 [4096][64]
#define OX4  5308416u    // conv3 partial q3 (+bias+residual)
#define OX4B 3473408u    // conv3 partial q2 (over dead yf)
#define PER_B 5570560u

#define NCH 64   // scan chunks
#define CL  64   // chunk length

// 1. xz[e,l] = sum_c in_proj_w[e,c] * seq[c,l].
__global__ __launch_bounds__(256) void kxz(
    const float* __restrict__ x, const float* __restrict__ wip,
    float* __restrict__ ws, int b0) {
  int bi = blockIdx.y, gb = b0 + bi;
  float* s = ws + (size_t)bi * PER_B;
  int bid = blockIdx.x;
  int h = bid >> 4, w = bid & 15;
  int tid = threadIdx.x;
  __shared__ float xs[64][16];
  for (int i = tid; i < 1024; i += 256) {
    int c = i >> 4, t = i & 15;
    xs[c][t] = x[(size_t)(gb * 64 + c) * NL + t * 256 + h * 16 + w];
  }
  __syncthreads();
  int e = tid;
  float acc[16];
#pragma unroll
  for (int t = 0; t < 16; ++t) acc[t] = 0.f;
  for (int c = 0; c < 64; ++c) {
    float wv = wip[e * 64 + c];
#pragma unroll
    for (int t = 0; t < 16; ++t) acc[t] = fmaf(wv, xs[c][t], acc[t]);
  }
  float4* dst = (float4*)(s + OXZ + (size_t)e * NL + h * 256 + w * 16);
#pragma unroll
  for (int q = 0; q < 4; ++q)
    dst[q] = make_float4(acc[q * 4], acc[q * 4 + 1], acc[q * 4 + 2], acc[q * 4 + 3]);
}

// 2. Fused prep per (bi, 32-l tile): dwconv+silu, x_dbl, delta, bct.
__global__ __launch_bounds__(256) void k2prep(
    const float* __restrict__ cwf, const float* __restrict__ cbf,
    const float* __restrict__ xpf, const float* __restrict__ dtwf,
    const float* __restrict__ dtbf,
    const float* __restrict__ cwb, const float* __restrict__ cbb,
    const float* __restrict__ xpb, const float* __restrict__ dtwb,
    const float* __restrict__ dtbb,
    float* __restrict__ ws) {
  int bi = blockIdx.y;
  float* s = ws + (size_t)bi * PER_B;
  int lt = blockIdx.x;
  int l0 = lt * 32;
  int l0b = (127 - lt) * 32;
  int tid = threadIdx.x;

  __shared__ float X[128][40];
  __shared__ float ucs[2][128][32];
  __shared__ float xds[2][40][33];

  for (int i = tid; i < 128 * 38; i += 256) {
    int d = i / 38, j = i - d * 38;
    int l = l0 - 3 + j;
    X[d][j] = (l >= 0 && l < NL) ? s[OXZ + (size_t)d * NL + l] : 0.f;
  }
  __syncthreads();

  for (int i = tid; i < 2 * 128 * 32; i += 256) {
    int br = i >> 12, rem = i & 4095;
    int d = rem >> 5, li = rem & 31;
    float a;
    if (br == 0) {
      a = cbf[d];
#pragma unroll
      for (int k = 0; k < 4; ++k) a = fmaf(cwf[d * 4 + k], X[d][li + k], a);
    } else {
      a = cbb[d];
#pragma unroll
      for (int k = 0; k < 4; ++k) a = fmaf(cwb[d * 4 + k], X[d][37 - li - k], a);
    }
    a = siluf_(a);
    ucs[br][d][li] = a;
    int lg = br ? (l0b + li) : (l0 + li);
    s[(br ? OUCB : OUCF) + (size_t)d * NL + lg] = a;
  }
  __syncthreads();

  for (int j = 0; j < 10; ++j) {
    int out = j * 256 + tid;
    int br = out / 1280;
    int rem = out - br * 1280;
    int e = rem >> 5, li = rem & 31;
    const float* xp = br ? xpb : xpf;
    float acc = 0.f;
    for (int d = 0; d < 128; ++d)
      acc = fmaf(xp[e * 128 + d], ucs[br][d][li], acc);
    xds[br][e][li] = acc;
  }
  __syncthreads();

  for (int i = tid; i < 2 * 128 * 32; i += 256) {
    int br = i >> 12, rem = i & 4095;
    int d = rem >> 5, li = rem & 31;
    const float* dtw = br ? dtwb : dtwf;
    float pre = (br ? dtbb : dtbf)[d];
#pragma unroll
    for (int r = 0; r < 8; ++r)
      pre = fmaf(dtw[d * 8 + r], xds[br][r][li], pre);
    int lg = br ? (l0b + li) : (l0 + li);
    s[(br ? ODLB : ODLF) + (size_t)d * NL + lg] = softplusf_(pre);
  }
  for (int i = tid; i < 2 * 32 * 32; i += 256) {
    int dir = i >> 10;
    int li = (i >> 5) & 31, k = i & 31;
    int lg = dir ? (l0b + li) : (l0 + li);
    s[OO2 + ((size_t)dir * 4096 + lg) * 32 + k] = xds[dir][8 + k][li];
  }
}

// 5a. Phase A: per-chunk local scan.
__global__ __launch_bounds__(64) void kscanA(
    const float* __restrict__ Alf, const float* __restrict__ Alb,
    float* __restrict__ ws) {
  int bi = blockIdx.y;
  float* s = ws + (size_t)bi * PER_B;
  int xid = blockIdx.x;
  int chunk = xid >> 6, dir = (xid >> 5) & 1, dblk = xid & 31;
  int n = threadIdx.x & 15, g = threadIdx.x >> 4;
  int d = dblk * 4 + g;
  const float* uc = s + (dir ? OUCB : OUCF) + (size_t)d * NL;
  const float* dl = s + (dir ? ODLB : ODLF) + (size_t)d * NL;
  const float* bct = s + OO2 + (size_t)dir * 4096 * 32;
  float A = -__expf((dir ? Alb : Alf)[d * 16 + n]);
  int l0 = chunk * CL;
  float P = 1.f, S = 0.f;
#pragma unroll 4
  for (int i = 0; i < CL; ++i) {
    int l = l0 + i;
    float dv = dl[l];
    float dA = __expf(dv * A);
    S = fmaf(dA, S, dv * bct[(size_t)l * 32 + n] * uc[l]);
    P *= dA;
  }
  size_t cidx = ((size_t)(chunk * 2 + dir) * 128 + d) * 16 + n;
  s[OO + cidx] = P;
  s[OO + 262144u + cidx] = S;
}

// 5b. Phase B: carry combine.
__global__ __launch_bounds__(64) void kscanB(float* __restrict__ ws) {
  int bi = blockIdx.y;
  float* s = ws + (size_t)bi * PER_B;
  int dir = blockIdx.x >> 5, dblk = blockIdx.x & 31;
  int tid = threadIdx.x;
  size_t base = (size_t)dir * 2048 + dblk * 64 + tid;
  float carry = 0.f;
#pragma unroll 4
  for (int c = 0; c < NCH; ++c) {
    size_t idx = (size_t)c * 4096 + base;
    float pv = s[OO + idx], sv = s[OO + 262144u + idx];
    s[OO + 262144u + idx] = carry;
    carry = fmaf(pv, carry, sv);
  }
}

// 5c. Phase C: seeded re-scan; y staged in LDS, coalesced stores.
__global__ __launch_bounds__(64) void kscanC(
    const float* __restrict__ Alf, const float* __restrict__ Df,
    const float* __restrict__ Alb, const float* __restrict__ Db,
    float* __restrict__ ws) {
  int bi = blockIdx.y;
  float* s = ws + (size_t)bi * PER_B;
  int xid = blockIdx.x;
  int chunk = xid >> 6, dir = (xid >> 5) & 1, dblk = xid & 31;
  int tid = threadIdx.x;
  int n = tid & 15, g = tid >> 4;
  int d = dblk * 4 + g;
  const float* uc = s + (dir ? OUCB : OUCF) + (size_t)d * NL;
  const float* dl = s + (dir ? ODLB : ODLF) + (size_t)d * NL;
  const float* bct = s + OO2 + (size_t)dir * 4096 * 32;
  float* ybase = s + (dir ? OYB : OYF);
  float A = -__expf((dir ? Alb : Alf)[d * 16 + n]);
  float Dv = (dir ? Db : Df)[d];
  size_t cidx = ((size_t)(chunk * 2 + dir) * 128 + d) * 16 + n;
  float h = s[OO + 262144u + cidx];
  int l0 = chunk * CL;
  __shared__ float ps[4][CL];
#pragma unroll 2
  for (int i = 0; i < CL; ++i) {
    int l = l0 + i;
    float dv = dl[l], uv = uc[l];
    float dA = __expf(dv * A);
    h = fmaf(dA, h, dv * bct[(size_t)l * 32 + n] * uv);
    float p = h * bct[(size_t)l * 32 + 16 + n];
    p += __shfl_xor(p, 1, 16);
    p += __shfl_xor(p, 2, 16);
    p += __shfl_xor(p, 4, 16);
    p += __shfl_xor(p, 8, 16);
    if (n == 0) ps[g][i] = fmaf(uv, Dv, p);
  }
#pragma unroll
  for (int dd = 0; dd < 4; ++dd)
    ybase[(size_t)(dblk * 4 + dd) * NL + l0 + tid] = ps[dd][tid];
}

// 6. Fused gate + out-proj. Block = 32-l tile.
// Phase1: ot[d][li] = (yf[d,l] + yb[d,L-1-l]) * silu(z[d,l]) -> LDS.
// Phase2: acc[8c] over 128 d from LDS. Phase3: transposed coalesced store.
__global__ __launch_bounds__(256) void koutg(
    const float* __restrict__ wout, float* __restrict__ ws) {
  int bi = blockIdx.y;
  float* s = ws + (size_t)bi * PER_B;
  int lt = blockIdx.x;  // 0..127
  int l0 = lt * 32;
  int tid = threadIdx.x;
  __shared__ float ot[128][32];   // 16 KB
  __shared__ float ot2[64][33];   // 8.4 KB
  for (int i = tid; i < 128 * 32; i += 256) {
    int d = i >> 5, li = i & 31;
    int l = l0 + li;
    float z = s[OXZ + (size_t)(128 + d) * NL + l];
    float v = s[OYF + (size_t)d * NL + l] + s[OYB + (size_t)d * NL + (NL - 1 - l)];
    ot[d][li] = v * siluf_(z);
  }
  __syncthreads();
  {
    int li = tid & 31, cg = tid >> 5;  // 8 groups of 8 c
    float acc[8];
#pragma unroll
    for (int j = 0; j < 8; ++j) acc[j] = 0.f;
    for (int d = 0; d < 128; ++d) {
      float xv = ot[d][li];
#pragma unroll
      for (int j = 0; j < 8; ++j)
        acc[j] = fmaf(wout[(cg * 8 + j) * 128 + d], xv, acc[j]);
    }
#pragma unroll
    for (int j = 0; j < 8; ++j) ot2[cg * 8 + j][li] = acc[j];
  }
  __syncthreads();
  for (int i = tid; i < 32 * 64; i += 256) {
    int li = i >> 6, c = i & 63;
    s[OO2 + (size_t)(l0 + li) * 64 + c] = ot2[c][li];
  }
}

// 7. conv3d partials. Grid = (t, hq, ciq): 256 blocks/slab (4/CU).
// 256 thr = 64co x 4h, 16 w each over 16-ci quarter. Xs = 20.7 KB.
// q3 -> OX4 (+bias+residual); q2 -> OX4B; q1 -> OXZ+262144; q0 -> OXZ.
__global__ __launch_bounds__(256) void kconv3(
    const float* __restrict__ pw, const float* __restrict__ pb,
    const float* __restrict__ xin, float* __restrict__ ws, int b0) {
  int bi = blockIdx.y, gb = b0 + bi;
  float* s = ws + (size_t)bi * PER_B;
  int t = blockIdx.x >> 4, hq = (blockIdx.x >> 2) & 3, ciq = blockIdx.x & 3;
  int h0 = hq * 4;
  int tid = threadIdx.x;
  int co = tid >> 2, hh = tid & 3;
  int h = h0 + hh;
  const float* xr = s + OO2;  // o2 bytes == (C,T,H,W)
  __shared__ float Xs[16][3][6][18];
  float acc[16];
#pragma unroll
  for (int w = 0; w < 16; ++w) acc[w] = 0.f;

  for (int i = tid; i < 16 * 324; i += 256) {
    int ci = i / 324;
    int rem = i - ci * 324;
    int tt = rem / 108;
    int rem2 = rem - tt * 108;
    int hh2 = rem2 / 18;
    int ww = rem2 - hh2 * 18;
    int ts = t + tt - 1, hs = h0 + hh2 - 1, wv = ww - 1;
    float v = 0.f;
    if (ts >= 0 && ts < 16 && hs >= 0 && hs < 16 && wv >= 0 && wv < 16)
      v = xr[(size_t)(ciq * 16 + ci) * NL + ts * 256 + hs * 16 + wv];
    Xs[ci][tt][hh2][ww] = v;
  }
  __syncthreads();
  const float* wc = pw + (co * 64 + ciq * 16) * 27;
  for (int ci = 0; ci < 16; ++ci) {
#pragma unroll
    for (int kt = 0; kt < 3; ++kt) {
#pragma unroll
      for (int kh = 0; kh < 3; ++kh) {
        const float* wr = wc + ci * 27 + kt * 9 + kh * 3;
        float wv0 = wr[0], wv1 = wr[1], wv2 = wr[2];
        const float* row = &Xs[ci][kt][hh + kh][0];
        float xp = row[0], xc = row[1];
#pragma unroll
        for (int w = 0; w < 16; ++w) {
          float xn = row[w + 2];
          acc[w] = fmaf(wv0, xp, fmaf(wv1, xc, fmaf(wv2, xn, acc[w])));
          xp = xc; xc = xn;
        }
      }
    }
  }
  size_t off = (size_t)co * NL + t * 256 + h * 16;
  if (ciq == 3) {
    float bias = pb[co];
    size_t ibase = (size_t)(gb * 64 + co) * NL + t * 256 + h * 16;
#pragma unroll
    for (int w = 0; w < 16; ++w)
      s[OX4 + off + w] = acc[w] + bias + xin[ibase + w];
  } else {
    size_t dsto = (ciq == 2) ? OX4B : (ciq == 1 ? (OXZ + 262144u) : OXZ);
#pragma unroll
    for (int w = 0; w < 16; ++w)
      s[dsto + off + w] = acc[w];
  }
}

// 8. knorm: LDS-tiled 1x1x1 channel mix over the 4-partial sum + norm_b.
__global__ __launch_bounds__(256) void knorm(
    const float* __restrict__ nw, const float* __restrict__ nb,
    float* __restrict__ out, float* __restrict__ ws, int b0) {
  int bi = blockIdx.y, gb = b0 + bi;
  float* s = ws + (size_t)bi * PER_B;
  int pt = blockIdx.x;
  int p0 = pt * 64;
  int tid = threadIdx.x;
  __shared__ float xs[64][64];
  for (int i = tid; i < 4096; i += 256) {
    int ci = i >> 6, p = i & 63;
    size_t o = (size_t)ci * NL + p0 + p;
    xs[ci][p] = s[OX4 + o] + s[OX4B + o] + s[OXZ + o] + s[OXZ + 262144u + o];
  }
  __syncthreads();
  int co = tid >> 2, pq = tid & 3;
  float acc[16];
#pragma unroll
  for (int j = 0; j < 16; ++j) acc[j] = 0.f;
  for (int ci = 0; ci < 64; ++ci) {
    float wv = nw[co * 64 + ci];
    const float* row = &xs[ci][pq * 16];
#pragma unroll
    for (int j = 0; j < 16; ++j) acc[j] = fmaf(wv, row[j], acc[j]);
  }
  float bias = nb[co];
  float4* dst = (float4*)(out + (size_t)(gb * 64 + co) * NL + p0 + pq * 16);
#pragma unroll
  for (int q = 0; q < 4; ++q)
    dst[q] = make_float4(acc[q * 4] + bias, acc[q * 4 + 1] + bias,
                         acc[q * 4 + 2] + bias, acc[q * 4 + 3] + bias);
}

// ---------------------------------------------------------------------------
extern "C" void kernel_launch(void* const* d_in, const int* in_sizes, int n_in,
                              void* d_out, int out_size, void* d_ws, size_t ws_size,
                              hipStream_t stream) {
  const float* x    = (const float*)d_in[0];
  const float* wip  = (const float*)d_in[1];
  const float* cwf  = (const float*)d_in[2];
  const float* cbf  = (const float*)d_in[3];
  const float* xpf  = (const float*)d_in[4];
  const float* dtwf = (const float*)d_in[5];
  const float* dtbf = (const float*)d_in[6];
  const float* Alf  = (const float*)d_in[7];
  const float* Df   = (const float*)d_in[8];
  const float* cwb  = (const float*)d_in[9];
  const float* cbb  = (const float*)d_in[10];
  const float* xpb  = (const float*)d_in[11];
  const float* dtwb = (const float*)d_in[12];
  const float* dtbb = (const float*)d_in[13];
  const float* Alb  = (const float*)d_in[14];
  const float* Db   = (const float*)d_in[15];
  const float* wout = (const float*)d_in[16];
  const float* pw   = (const float*)d_in[17];
  const float* pb   = (const float*)d_in[18];
  const float* nw   = (const float*)d_in[19];
  const float* nb   = (const float*)d_in[20];

  const size_t PER_B_BYTES = (size_t)PER_B * 4;  // 22,282,240 per batch slab
  int bcnt;
  if (ws_size >= 4 * PER_B_BYTES) bcnt = 4;
  else if (ws_size >= PER_B_BYTES) bcnt = 1;
  else return;
  int passes = 4 / bcnt;

  float* ws = (float*)d_ws;
  for (int p = 0; p < passes; ++p) {
    int b0 = p * bcnt;
    kxz   <<<dim3(256, bcnt), 256, 0, stream>>>(x, wip, ws, b0);
    k2prep<<<dim3(128, bcnt), 256, 0, stream>>>(cwf, cbf, xpf, dtwf, dtbf,
                                                cwb, cbb, xpb, dtwb, dtbb, ws);
    kscanA<<<dim3(4096, bcnt), 64, 0, stream>>>(Alf, Alb, ws);
    kscanB<<<dim3(64, bcnt), 64, 0, stream>>>(ws);
    kscanC<<<dim3(4096, bcnt), 64, 0, stream>>>(Alf, Df, Alb, Db, ws);
    koutg <<<dim3(128, bcnt), 256, 0, stream>>>(wout, ws);
    kconv3<<<dim3(256, bcnt), 256, 0, stream>>>(pw, pb, x, ws, b0);
    knorm <<<dim3(64, bcnt), 256, 0, stream>>>(nw, nb, (float*)d_out, ws, b0);
  }
}

// Round 14
// 365.425 us; speedup vs baseline: 1.3661x; 1.0211x over previous
//
#include <hip/hip_runtime.h>

// ---------------------------------------------------------------------------
// Bidirectional Mamba block, MI355X. Round 13:
//  - kscanA/kscanC: 16 d-rows/block, chunk bct staged in LDS (traffic /4),
//    ps staging padded [16][65] (kills 2.1M bank conflicts)
//  - k2prep: xds unioned over dead X (52KB -> 3 blocks/CU), float4 x_dbl
// Shapes: B=4, C=64, D=128, L=4096 (l = h*256 + w*16 + t), N=16, R=8.
// ---------------------------------------------------------------------------

#define NL 4096

__device__ __forceinline__ float siluf_(float x) { return x / (1.f + __expf(-x)); }
__device__ __forceinline__ float softplusf_(float x) {
  return (x > 20.f) ? x : log1pf(__expf(x));
}

// Per-b slab offsets (fp32 elements)
#define OXZ  0u          // xz [256][4096]; rows become conv3 partials q0/q1
#define OUCF 1048576u    // ucf  [128][4096]
#define OUCB 1572864u    // ucb  [128][4096]  (flipped coords)
#define ODLF 2424832u    // dlf  [128][4096]
#define ODLB 2949120u    // dlb  [128][4096]  (flipped coords)
#define OYF  3473408u    // yf [128][4096]; first half becomes conv3 partial q2
#define OYB  3997696u    // yb   [128][4096]  (flipped coords)
#define OO   4521984u    // scan scratch: P [262144] S [262144]
#define OO2  5046272u    // bct [2][4096][32] until kscanC; then o2 [4096][64]
#define OX4  5308416u    // conv3 partial q3 (+bias+residual)
#define OX4B 3473408u    // conv3 partial q2 (over dead yf)
#define PER_B 5570560u

#define NCH 64   // scan chunks
#define CL  64   // chunk length

// 1. xz[e,l] = sum_c in_proj_w[e,c] * seq[c,l].
__global__ __launch_bounds__(256) void kxz(
    const float* __restrict__ x, const float* __restrict__ wip,
    float* __restrict__ ws, int b0) {
  int bi = blockIdx.y, gb = b0 + bi;
  float* s = ws + (size_t)bi * PER_B;
  int bid = blockIdx.x;
  int h = bid >> 4, w = bid & 15;
  int tid = threadIdx.x;
  __shared__ float xs[64][16];
  for (int i = tid; i < 1024; i += 256) {
    int c = i >> 4, t = i & 15;
    xs[c][t] = x[(size_t)(gb * 64 + c) * NL + t * 256 + h * 16 + w];
  }
  __syncthreads();
  int e = tid;
  float acc[16];
#pragma unroll
  for (int t = 0; t < 16; ++t) acc[t] = 0.f;
  for (int c = 0; c < 64; ++c) {
    float wv = wip[e * 64 + c];
#pragma unroll
    for (int t = 0; t < 16; ++t) acc[t] = fmaf(wv, xs[c][t], acc[t]);
  }
  float4* dst = (float4*)(s + OXZ + (size_t)e * NL + h * 256 + w * 16);
#pragma unroll
  for (int q = 0; q < 4; ++q)
    dst[q] = make_float4(acc[q * 4], acc[q * 4 + 1], acc[q * 4 + 2], acc[q * 4 + 3]);
}

// 2. Fused prep per (bi, 32-l tile): dwconv+silu, x_dbl (float4), delta, bct.
// LDS: pool (X -> xds union) 20KB + ucs 32KB = 52KB -> 3 blocks/CU.
__global__ __launch_bounds__(256) void k2prep(
    const float* __restrict__ cwf, const float* __restrict__ cbf,
    const float* __restrict__ xpf, const float* __restrict__ dtwf,
    const float* __restrict__ dtbf,
    const float* __restrict__ cwb, const float* __restrict__ cbb,
    const float* __restrict__ xpb, const float* __restrict__ dtwb,
    const float* __restrict__ dtbb,
    float* __restrict__ ws) {
  int bi = blockIdx.y;
  float* s = ws + (size_t)bi * PER_B;
  int lt = blockIdx.x;
  int l0 = lt * 32;
  int l0b = (127 - lt) * 32;
  int tid = threadIdx.x;

  __shared__ float pool[128 * 40];   // X[128][40] during dwconv; xds after
  __shared__ float ucs[2][128][32];
  float (*X)[40] = (float(*)[40])pool;

  for (int i = tid; i < 128 * 38; i += 256) {
    int d = i / 38, j = i - d * 38;
    int l = l0 - 3 + j;
    X[d][j] = (l >= 0 && l < NL) ? s[OXZ + (size_t)d * NL + l] : 0.f;
  }
  __syncthreads();

  // dwconv + silu (X read here; dead after)
  for (int i = tid; i < 2 * 128 * 32; i += 256) {
    int br = i >> 12, rem = i & 4095;
    int d = rem >> 5, li = rem & 31;
    float a;
    if (br == 0) {
      a = cbf[d];
#pragma unroll
      for (int k = 0; k < 4; ++k) a = fmaf(cwf[d * 4 + k], X[d][li + k], a);
    } else {
      a = cbb[d];
#pragma unroll
      for (int k = 0; k < 4; ++k) a = fmaf(cwb[d * 4 + k], X[d][37 - li - k], a);
    }
    a = siluf_(a);
    ucs[br][d][li] = a;
    int lg = br ? (l0b + li) : (l0 + li);
    s[(br ? OUCB : OUCF) + (size_t)d * NL + lg] = a;
  }
  __syncthreads();  // X dead; pool becomes xds [2][40][33]

  // x_dbl: float4 over li. 640 items = (br, e<40, liq<8).
  float* xds = pool;
  for (int i = tid; i < 640; i += 256) {
    int br = i / 320;
    int rem = i - br * 320;
    int e = rem >> 3, liq = rem & 7;
    const float* xp = br ? xpb : xpf;
    float4 acc = make_float4(0.f, 0.f, 0.f, 0.f);
    for (int d = 0; d < 128; ++d) {
      float wv = xp[e * 128 + d];
      const float4 u4 = *(const float4*)&ucs[br][d][liq * 4];
      acc.x = fmaf(wv, u4.x, acc.x);
      acc.y = fmaf(wv, u4.y, acc.y);
      acc.z = fmaf(wv, u4.z, acc.z);
      acc.w = fmaf(wv, u4.w, acc.w);
    }
    float* dst = &xds[(br * 40 + e) * 33 + liq * 4];
    dst[0] = acc.x; dst[1] = acc.y; dst[2] = acc.z; dst[3] = acc.w;
  }
  __syncthreads();

  // delta
  for (int i = tid; i < 2 * 128 * 32; i += 256) {
    int br = i >> 12, rem = i & 4095;
    int d = rem >> 5, li = rem & 31;
    const float* dtw = br ? dtwb : dtwf;
    float pre = (br ? dtbb : dtbf)[d];
#pragma unroll
    for (int r = 0; r < 8; ++r)
      pre = fmaf(dtw[d * 8 + r], xds[(br * 40 + r) * 33 + li], pre);
    int lg = br ? (l0b + li) : (l0 + li);
    s[(br ? ODLB : ODLF) + (size_t)d * NL + lg] = softplusf_(pre);
  }
  // bct
  for (int i = tid; i < 2 * 32 * 32; i += 256) {
    int dir = i >> 10;
    int li = (i >> 5) & 31, k = i & 31;
    int lg = dir ? (l0b + li) : (l0 + li);
    s[OO2 + ((size_t)dir * 4096 + lg) * 32 + k] = xds[(dir * 40 + 8 + k) * 33 + li];
  }
}

// 5a. Phase A: 16 d-rows/block (256 thr = 4 waves x 4 d x 16 n); chunk bct
// staged once in LDS. Grid x = chunk*16 + dir*8 + d8 (1024/slab).
__global__ __launch_bounds__(256) void kscanA(
    const float* __restrict__ Alf, const float* __restrict__ Alb,
    float* __restrict__ ws) {
  int bi = blockIdx.y;
  float* s = ws + (size_t)bi * PER_B;
  int xid = blockIdx.x;
  int chunk = xid >> 4, dir = (xid >> 3) & 1, d8 = xid & 7;
  int tid = threadIdx.x;
  int wv = tid >> 6, lane = tid & 63;
  int n = lane & 15, g = lane >> 4;
  int d = d8 * 16 + wv * 4 + g;
  int l0 = chunk * CL;
  __shared__ float bl[CL * 32];
  {
    const float* bct = s + OO2 + ((size_t)dir * 4096 + l0) * 32;
    for (int i = tid; i < CL * 32; i += 256) bl[i] = bct[i];
  }
  __syncthreads();
  const float* uc = s + (dir ? OUCB : OUCF) + (size_t)d * NL + l0;
  const float* dl = s + (dir ? ODLB : ODLF) + (size_t)d * NL + l0;
  float A = -__expf((dir ? Alb : Alf)[d * 16 + n]);
  float P = 1.f, S = 0.f;
#pragma unroll 4
  for (int i = 0; i < CL; ++i) {
    float dv = dl[i];
    float dA = __expf(dv * A);
    S = fmaf(dA, S, dv * bl[i * 32 + n] * uc[i]);
    P *= dA;
  }
  size_t cidx = ((size_t)(chunk * 2 + dir) * 128 + d) * 16 + n;
  s[OO + cidx] = P;
  s[OO + 262144u + cidx] = S;
}

// 5b. Phase B: carry combine.
__global__ __launch_bounds__(64) void kscanB(float* __restrict__ ws) {
  int bi = blockIdx.y;
  float* s = ws + (size_t)bi * PER_B;
  int dir = blockIdx.x >> 5, dblk = blockIdx.x & 31;
  int tid = threadIdx.x;
  size_t base = (size_t)dir * 2048 + dblk * 64 + tid;
  float carry = 0.f;
#pragma unroll 4
  for (int c = 0; c < NCH; ++c) {
    size_t idx = (size_t)c * 4096 + base;
    float pv = s[OO + idx], sv = s[OO + 262144u + idx];
    s[OO + 262144u + idx] = carry;
    carry = fmaf(pv, carry, sv);
  }
}

// 5c. Phase C: seeded re-scan; 16 d-rows/block; bct in LDS; ps[16][65].
__global__ __launch_bounds__(256) void kscanC(
    const float* __restrict__ Alf, const float* __restrict__ Df,
    const float* __restrict__ Alb, const float* __restrict__ Db,
    float* __restrict__ ws) {
  int bi = blockIdx.y;
  float* s = ws + (size_t)bi * PER_B;
  int xid = blockIdx.x;
  int chunk = xid >> 4, dir = (xid >> 3) & 1, d8 = xid & 7;
  int tid = threadIdx.x;
  int wv = tid >> 6, lane = tid & 63;
  int n = lane & 15, g = lane >> 4;
  int d = d8 * 16 + wv * 4 + g;
  int l0 = chunk * CL;
  __shared__ float bl[CL * 32];
  __shared__ float ps[16][65];
  {
    const float* bct = s + OO2 + ((size_t)dir * 4096 + l0) * 32;
    for (int i = tid; i < CL * 32; i += 256) bl[i] = bct[i];
  }
  __syncthreads();
  const float* uc = s + (dir ? OUCB : OUCF) + (size_t)d * NL + l0;
  const float* dl = s + (dir ? ODLB : ODLF) + (size_t)d * NL + l0;
  float* ybase = s + (dir ? OYB : OYF);
  float A = -__expf((dir ? Alb : Alf)[d * 16 + n]);
  float Dv = (dir ? Db : Df)[d];
  size_t cidx = ((size_t)(chunk * 2 + dir) * 128 + d) * 16 + n;
  float h = s[OO + 262144u + cidx];
#pragma unroll 2
  for (int i = 0; i < CL; ++i) {
    float dv = dl[i], uv = uc[i];
    float dA = __expf(dv * A);
    h = fmaf(dA, h, dv * bl[i * 32 + n] * uv);
    float p = h * bl[i * 32 + 16 + n];
    p += __shfl_xor(p, 1, 16);
    p += __shfl_xor(p, 2, 16);
    p += __shfl_xor(p, 4, 16);
    p += __shfl_xor(p, 8, 16);
    if (n == 0) ps[wv * 4 + g][i] = fmaf(uv, Dv, p);
  }
  __syncthreads();
  for (int i = tid; i < 16 * CL; i += 256) {
    int row = i >> 6, col = i & 63;
    ybase[(size_t)(d8 * 16 + row) * NL + l0 + col] = ps[row][col];
  }
}

// 6. Fused gate + out-proj. Block = 32-l tile.
__global__ __launch_bounds__(256) void koutg(
    const float* __restrict__ wout, float* __restrict__ ws) {
  int bi = blockIdx.y;
  float* s = ws + (size_t)bi * PER_B;
  int lt = blockIdx.x;
  int l0 = lt * 32;
  int tid = threadIdx.x;
  __shared__ float ot[128][32];
  __shared__ float ot2[64][33];
  for (int i = tid; i < 128 * 32; i += 256) {
    int d = i >> 5, li = i & 31;
    int l = l0 + li;
    float z = s[OXZ + (size_t)(128 + d) * NL + l];
    float v = s[OYF + (size_t)d * NL + l] + s[OYB + (size_t)d * NL + (NL - 1 - l)];
    ot[d][li] = v * siluf_(z);
  }
  __syncthreads();
  {
    int li = tid & 31, cg = tid >> 5;
    float acc[8];
#pragma unroll
    for (int j = 0; j < 8; ++j) acc[j] = 0.f;
    for (int d = 0; d < 128; ++d) {
      float xv = ot[d][li];
#pragma unroll
      for (int j = 0; j < 8; ++j)
        acc[j] = fmaf(wout[(cg * 8 + j) * 128 + d], xv, acc[j]);
    }
#pragma unroll
    for (int j = 0; j < 8; ++j) ot2[cg * 8 + j][li] = acc[j];
  }
  __syncthreads();
  for (int i = tid; i < 32 * 64; i += 256) {
    int li = i >> 6, c = i & 63;
    s[OO2 + (size_t)(l0 + li) * 64 + c] = ot2[c][li];
  }
}

// 7. conv3d partials. Grid = (t, hq, ciq): 256 blocks/slab (4/CU).
__global__ __launch_bounds__(256) void kconv3(
    const float* __restrict__ pw, const float* __restrict__ pb,
    const float* __restrict__ xin, float* __restrict__ ws, int b0) {
  int bi = blockIdx.y, gb = b0 + bi;
  float* s = ws + (size_t)bi * PER_B;
  int t = blockIdx.x >> 4, hq = (blockIdx.x >> 2) & 3, ciq = blockIdx.x & 3;
  int h0 = hq * 4;
  int tid = threadIdx.x;
  int co = tid >> 2, hh = tid & 3;
  int h = h0 + hh;
  const float* xr = s + OO2;
  __shared__ float Xs[16][3][6][18];
  float acc[16];
#pragma unroll
  for (int w = 0; w < 16; ++w) acc[w] = 0.f;

  for (int i = tid; i < 16 * 324; i += 256) {
    int ci = i / 324;
    int rem = i - ci * 324;
    int tt = rem / 108;
    int rem2 = rem - tt * 108;
    int hh2 = rem2 / 18;
    int ww = rem2 - hh2 * 18;
    int ts = t + tt - 1, hs = h0 + hh2 - 1, wv = ww - 1;
    float v = 0.f;
    if (ts >= 0 && ts < 16 && hs >= 0 && hs < 16 && wv >= 0 && wv < 16)
      v = xr[(size_t)(ciq * 16 + ci) * NL + ts * 256 + hs * 16 + wv];
    Xs[ci][tt][hh2][ww] = v;
  }
  __syncthreads();
  const float* wc = pw + (co * 64 + ciq * 16) * 27;
  for (int ci = 0; ci < 16; ++ci) {
#pragma unroll
    for (int kt = 0; kt < 3; ++kt) {
#pragma unroll
      for (int kh = 0; kh < 3; ++kh) {
        const float* wr = wc + ci * 27 + kt * 9 + kh * 3;
        float wv0 = wr[0], wv1 = wr[1], wv2 = wr[2];
        const float* row = &Xs[ci][kt][hh + kh][0];
        float xp = row[0], xc = row[1];
#pragma unroll
        for (int w = 0; w < 16; ++w) {
          float xn = row[w + 2];
          acc[w] = fmaf(wv0, xp, fmaf(wv1, xc, fmaf(wv2, xn, acc[w])));
          xp = xc; xc = xn;
        }
      }
    }
  }
  size_t off = (size_t)co * NL + t * 256 + h * 16;
  if (ciq == 3) {
    float bias = pb[co];
    size_t ibase = (size_t)(gb * 64 + co) * NL + t * 256 + h * 16;
#pragma unroll
    for (int w = 0; w < 16; ++w)
      s[OX4 + off + w] = acc[w] + bias + xin[ibase + w];
  } else {
    size_t dsto = (ciq == 2) ? OX4B : (ciq == 1 ? (OXZ + 262144u) : OXZ);
#pragma unroll
    for (int w = 0; w < 16; ++w)
      s[dsto + off + w] = acc[w];
  }
}

// 8. knorm: LDS-tiled 1x1x1 channel mix over the 4-partial sum + norm_b.
__global__ __launch_bounds__(256) void knorm(
    const float* __restrict__ nw, const float* __restrict__ nb,
    float* __restrict__ out, float* __restrict__ ws, int b0) {
  int bi = blockIdx.y, gb = b0 + bi;
  float* s = ws + (size_t)bi * PER_B;
  int pt = blockIdx.x;
  int p0 = pt * 64;
  int tid = threadIdx.x;
  __shared__ float xs[64][64];
  for (int i = tid; i < 4096; i += 256) {
    int ci = i >> 6, p = i & 63;
    size_t o = (size_t)ci * NL + p0 + p;
    xs[ci][p] = s[OX4 + o] + s[OX4B + o] + s[OXZ + o] + s[OXZ + 262144u + o];
  }
  __syncthreads();
  int co = tid >> 2, pq = tid & 3;
  float acc[16];
#pragma unroll
  for (int j = 0; j < 16; ++j) acc[j] = 0.f;
  for (int ci = 0; ci < 64; ++ci) {
    float wv = nw[co * 64 + ci];
    const float* row = &xs[ci][pq * 16];
#pragma unroll
    for (int j = 0; j < 16; ++j) acc[j] = fmaf(wv, row[j], acc[j]);
  }
  float bias = nb[co];
  float4* dst = (float4*)(out + (size_t)(gb * 64 + co) * NL + p0 + pq * 16);
#pragma unroll
  for (int q = 0; q < 4; ++q)
    dst[q] = make_float4(acc[q * 4] + bias, acc[q * 4 + 1] + bias,
                         acc[q * 4 + 2] + bias, acc[q * 4 + 3] + bias);
}

// ---------------------------------------------------------------------------
extern "C" void kernel_launch(void* const* d_in, const int* in_sizes, int n_in,
                              void* d_out, int out_size, void* d_ws, size_t ws_size,
                              hipStream_t stream) {
  const float* x    = (const float*)d_in[0];
  const float* wip  = (const float*)d_in[1];
  const float* cwf  = (const float*)d_in[2];
  const float* cbf  = (const float*)d_in[3];
  const float* xpf  = (const float*)d_in[4];
  const float* dtwf = (const float*)d_in[5];
  const float* dtbf = (const float*)d_in[6];
  const float* Alf  = (const float*)d_in[7];
  const float* Df   = (const float*)d_in[8];
  const float* cwb  = (const float*)d_in[9];
  const float* cbb  = (const float*)d_in[10];
  const float* xpb  = (const float*)d_in[11];
  const float* dtwb = (const float*)d_in[12];
  const float* dtbb = (const float*)d_in[13];
  const float* Alb  = (const float*)d_in[14];
  const float* Db   = (const float*)d_in[15];
  const float* wout = (const float*)d_in[16];
  const float* pw   = (const float*)d_in[17];
  const float* pb   = (const float*)d_in[18];
  const float* nw   = (const float*)d_in[19];
  const float* nb   = (const float*)d_in[20];

  const size_t PER_B_BYTES = (size_t)PER_B * 4;  // 22,282,240 per batch slab
  int bcnt;
  if (ws_size >= 4 * PER_B_BYTES) bcnt = 4;
  else if (ws_size >= PER_B_BYTES) bcnt = 1;
  else return;
  int passes = 4 / bcnt;

  float* ws = (float*)d_ws;
  for (int p = 0; p < passes; ++p) {
    int b0 = p * bcnt;
    kxz   <<<dim3(256, bcnt), 256, 0, stream>>>(x, wip, ws, b0);
    k2prep<<<dim3(128, bcnt), 256, 0, stream>>>(cwf, cbf, xpf, dtwf, dtbf,
                                                cwb, cbb, xpb, dtwb, dtbb, ws);
    kscanA<<<dim3(1024, bcnt), 256, 0, stream>>>(Alf, Alb, ws);
    kscanB<<<dim3(64, bcnt), 64, 0, stream>>>(ws);
    kscanC<<<dim3(1024, bcnt), 256, 0, stream>>>(Alf, Df, Alb, Db, ws);
    koutg <<<dim3(128, bcnt), 256, 0, stream>>>(wout, ws);
    kconv3<<<dim3(256, bcnt), 256, 0, stream>>>(pw, pb, x, ws, b0);
    knorm <<<dim3(64, bcnt), 256, 0, stream>>>(nw, nb, (float*)d_out, ws, b0);
  }
}

// Round 15
// 344.631 us; speedup vs baseline: 1.4485x; 1.0603x over previous
//
#include <hip/hip_runtime.h>

// ---------------------------------------------------------------------------
// Bidirectional Mamba block, MI355X. Round 14: kscanC n-reduction via DPP
// row rotations (VALU pipe) instead of 4x __shfl_xor (DS pipe). R13 analysis:
// kscanC was DS-pipe bound (6 DS ops/lane-iter ~31us); now 2.
// Everything else identical to passing R13.
// Shapes: B=4, C=64, D=128, L=4096 (l = h*256 + w*16 + t), N=16, R=8.
// ---------------------------------------------------------------------------

#define NL 4096

__device__ __forceinline__ float siluf_(float x) { return x / (1.f + __expf(-x)); }
__device__ __forceinline__ float softplusf_(float x) {
  return (x > 20.f) ? x : log1pf(__expf(x));
}

// Sum over the 16-lane DPP row via rotations 1,2,4,8 (VALU pipe, no DS).
// After the four accumulating rotations every lane holds the row sum.
__device__ __forceinline__ float rowsum16_(float p) {
  int q;
  q = __builtin_amdgcn_mov_dpp(__float_as_int(p), 0x121, 0xf, 0xf, false);
  p += __int_as_float(q);  // + ror 1
  q = __builtin_amdgcn_mov_dpp(__float_as_int(p), 0x122, 0xf, 0xf, false);
  p += __int_as_float(q);  // + ror 2
  q = __builtin_amdgcn_mov_dpp(__float_as_int(p), 0x124, 0xf, 0xf, false);
  p += __int_as_float(q);  // + ror 4
  q = __builtin_amdgcn_mov_dpp(__float_as_int(p), 0x128, 0xf, 0xf, false);
  p += __int_as_float(q);  // + ror 8
  return p;
}

// Per-b slab offsets (fp32 elements)
#define OXZ  0u          // xz [256][4096]; rows become conv3 partials q0/q1
#define OUCF 1048576u    // ucf  [128][4096]
#define OUCB 1572864u    // ucb  [128][4096]  (flipped coords)
#define ODLF 2424832u    // dlf  [128][4096]
#define ODLB 2949120u    // dlb  [128][4096]  (flipped coords)
#define OYF  3473408u    // yf [128][4096]; first half becomes conv3 partial q2
#define OYB  3997696u    // yb   [128][4096]  (flipped coords)
#define OO   4521984u    // scan scratch: P [262144] S [262144]
#define OO2  5046272u    // bct [2][4096][32] until kscanC; then o2 [4096][64]
#define OX4  5308416u    // conv3 partial q3 (+bias+residual)
#define OX4B 3473408u    // conv3 partial q2 (over dead yf)
#define PER_B 5570560u

#define NCH 64   // scan chunks
#define CL  64   // chunk length

// 1. xz[e,l] = sum_c in_proj_w[e,c] * seq[c,l].
__global__ __launch_bounds__(256) void kxz(
    const float* __restrict__ x, const float* __restrict__ wip,
    float* __restrict__ ws, int b0) {
  int bi = blockIdx.y, gb = b0 + bi;
  float* s = ws + (size_t)bi * PER_B;
  int bid = blockIdx.x;
  int h = bid >> 4, w = bid & 15;
  int tid = threadIdx.x;
  __shared__ float xs[64][16];
  for (int i = tid; i < 1024; i += 256) {
    int c = i >> 4, t = i & 15;
    xs[c][t] = x[(size_t)(gb * 64 + c) * NL + t * 256 + h * 16 + w];
  }
  __syncthreads();
  int e = tid;
  float acc[16];
#pragma unroll
  for (int t = 0; t < 16; ++t) acc[t] = 0.f;
  for (int c = 0; c < 64; ++c) {
    float wv = wip[e * 64 + c];
#pragma unroll
    for (int t = 0; t < 16; ++t) acc[t] = fmaf(wv, xs[c][t], acc[t]);
  }
  float4* dst = (float4*)(s + OXZ + (size_t)e * NL + h * 256 + w * 16);
#pragma unroll
  for (int q = 0; q < 4; ++q)
    dst[q] = make_float4(acc[q * 4], acc[q * 4 + 1], acc[q * 4 + 2], acc[q * 4 + 3]);
}

// 2. Fused prep per (bi, 32-l tile): dwconv+silu, x_dbl (float4), delta, bct.
__global__ __launch_bounds__(256) void k2prep(
    const float* __restrict__ cwf, const float* __restrict__ cbf,
    const float* __restrict__ xpf, const float* __restrict__ dtwf,
    const float* __restrict__ dtbf,
    const float* __restrict__ cwb, const float* __restrict__ cbb,
    const float* __restrict__ xpb, const float* __restrict__ dtwb,
    const float* __restrict__ dtbb,
    float* __restrict__ ws) {
  int bi = blockIdx.y;
  float* s = ws + (size_t)bi * PER_B;
  int lt = blockIdx.x;
  int l0 = lt * 32;
  int l0b = (127 - lt) * 32;
  int tid = threadIdx.x;

  __shared__ float pool[128 * 40];   // X[128][40] during dwconv; xds after
  __shared__ float ucs[2][128][32];
  float (*X)[40] = (float(*)[40])pool;

  for (int i = tid; i < 128 * 38; i += 256) {
    int d = i / 38, j = i - d * 38;
    int l = l0 - 3 + j;
    X[d][j] = (l >= 0 && l < NL) ? s[OXZ + (size_t)d * NL + l] : 0.f;
  }
  __syncthreads();

  for (int i = tid; i < 2 * 128 * 32; i += 256) {
    int br = i >> 12, rem = i & 4095;
    int d = rem >> 5, li = rem & 31;
    float a;
    if (br == 0) {
      a = cbf[d];
#pragma unroll
      for (int k = 0; k < 4; ++k) a = fmaf(cwf[d * 4 + k], X[d][li + k], a);
    } else {
      a = cbb[d];
#pragma unroll
      for (int k = 0; k < 4; ++k) a = fmaf(cwb[d * 4 + k], X[d][37 - li - k], a);
    }
    a = siluf_(a);
    ucs[br][d][li] = a;
    int lg = br ? (l0b + li) : (l0 + li);
    s[(br ? OUCB : OUCF) + (size_t)d * NL + lg] = a;
  }
  __syncthreads();  // X dead; pool becomes xds [2][40][33]

  float* xds = pool;
  for (int i = tid; i < 640; i += 256) {
    int br = i / 320;
    int rem = i - br * 320;
    int e = rem >> 3, liq = rem & 7;
    const float* xp = br ? xpb : xpf;
    float4 acc = make_float4(0.f, 0.f, 0.f, 0.f);
    for (int d = 0; d < 128; ++d) {
      float wv = xp[e * 128 + d];
      const float4 u4 = *(const float4*)&ucs[br][d][liq * 4];
      acc.x = fmaf(wv, u4.x, acc.x);
      acc.y = fmaf(wv, u4.y, acc.y);
      acc.z = fmaf(wv, u4.z, acc.z);
      acc.w = fmaf(wv, u4.w, acc.w);
    }
    float* dst = &xds[(br * 40 + e) * 33 + liq * 4];
    dst[0] = acc.x; dst[1] = acc.y; dst[2] = acc.z; dst[3] = acc.w;
  }
  __syncthreads();

  for (int i = tid; i < 2 * 128 * 32; i += 256) {
    int br = i >> 12, rem = i & 4095;
    int d = rem >> 5, li = rem & 31;
    const float* dtw = br ? dtwb : dtwf;
    float pre = (br ? dtbb : dtbf)[d];
#pragma unroll
    for (int r = 0; r < 8; ++r)
      pre = fmaf(dtw[d * 8 + r], xds[(br * 40 + r) * 33 + li], pre);
    int lg = br ? (l0b + li) : (l0 + li);
    s[(br ? ODLB : ODLF) + (size_t)d * NL + lg] = softplusf_(pre);
  }
  for (int i = tid; i < 2 * 32 * 32; i += 256) {
    int dir = i >> 10;
    int li = (i >> 5) & 31, k = i & 31;
    int lg = dir ? (l0b + li) : (l0 + li);
    s[OO2 + ((size_t)dir * 4096 + lg) * 32 + k] = xds[(dir * 40 + 8 + k) * 33 + li];
  }
}

// 5a. Phase A: 16 d-rows/block; chunk bct staged once in LDS.
__global__ __launch_bounds__(256) void kscanA(
    const float* __restrict__ Alf, const float* __restrict__ Alb,
    float* __restrict__ ws) {
  int bi = blockIdx.y;
  float* s = ws + (size_t)bi * PER_B;
  int xid = blockIdx.x;
  int chunk = xid >> 4, dir = (xid >> 3) & 1, d8 = xid & 7;
  int tid = threadIdx.x;
  int wv = tid >> 6, lane = tid & 63;
  int n = lane & 15, g = lane >> 4;
  int d = d8 * 16 + wv * 4 + g;
  int l0 = chunk * CL;
  __shared__ float bl[CL * 32];
  {
    const float* bct = s + OO2 + ((size_t)dir * 4096 + l0) * 32;
    for (int i = tid; i < CL * 32; i += 256) bl[i] = bct[i];
  }
  __syncthreads();
  const float* uc = s + (dir ? OUCB : OUCF) + (size_t)d * NL + l0;
  const float* dl = s + (dir ? ODLB : ODLF) + (size_t)d * NL + l0;
  float A = -__expf((dir ? Alb : Alf)[d * 16 + n]);
  float P = 1.f, S = 0.f;
#pragma unroll 4
  for (int i = 0; i < CL; ++i) {
    float dv = dl[i];
    float dA = __expf(dv * A);
    S = fmaf(dA, S, dv * bl[i * 32 + n] * uc[i]);
    P *= dA;
  }
  size_t cidx = ((size_t)(chunk * 2 + dir) * 128 + d) * 16 + n;
  s[OO + cidx] = P;
  s[OO + 262144u + cidx] = S;
}

// 5b. Phase B: carry combine.
__global__ __launch_bounds__(64) void kscanB(float* __restrict__ ws) {
  int bi = blockIdx.y;
  float* s = ws + (size_t)bi * PER_B;
  int dir = blockIdx.x >> 5, dblk = blockIdx.x & 31;
  int tid = threadIdx.x;
  size_t base = (size_t)dir * 2048 + dblk * 64 + tid;
  float carry = 0.f;
#pragma unroll 4
  for (int c = 0; c < NCH; ++c) {
    size_t idx = (size_t)c * 4096 + base;
    float pv = s[OO + idx], sv = s[OO + 262144u + idx];
    s[OO + 262144u + idx] = carry;
    carry = fmaf(pv, carry, sv);
  }
}

// 5c. Phase C: seeded re-scan; 16 d-rows/block; bct in LDS; DPP row-sum
// (VALU pipe) replaces the 4x shfl_xor DS ops; ps[16][65] staging.
__global__ __launch_bounds__(256) void kscanC(
    const float* __restrict__ Alf, const float* __restrict__ Df,
    const float* __restrict__ Alb, const float* __restrict__ Db,
    float* __restrict__ ws) {
  int bi = blockIdx.y;
  float* s = ws + (size_t)bi * PER_B;
  int xid = blockIdx.x;
  int chunk = xid >> 4, dir = (xid >> 3) & 1, d8 = xid & 7;
  int tid = threadIdx.x;
  int wv = tid >> 6, lane = tid & 63;
  int n = lane & 15, g = lane >> 4;
  int d = d8 * 16 + wv * 4 + g;
  int l0 = chunk * CL;
  __shared__ float bl[CL * 32];
  __shared__ float ps[16][65];
  {
    const float* bct = s + OO2 + ((size_t)dir * 4096 + l0) * 32;
    for (int i = tid; i < CL * 32; i += 256) bl[i] = bct[i];
  }
  __syncthreads();
  const float* uc = s + (dir ? OUCB : OUCF) + (size_t)d * NL + l0;
  const float* dl = s + (dir ? ODLB : ODLF) + (size_t)d * NL + l0;
  float* ybase = s + (dir ? OYB : OYF);
  float A = -__expf((dir ? Alb : Alf)[d * 16 + n]);
  float Dv = (dir ? Db : Df)[d];
  size_t cidx = ((size_t)(chunk * 2 + dir) * 128 + d) * 16 + n;
  float h = s[OO + 262144u + cidx];
#pragma unroll 2
  for (int i = 0; i < CL; ++i) {
    float dv = dl[i], uv = uc[i];
    float dA = __expf(dv * A);
    h = fmaf(dA, h, dv * bl[i * 32 + n] * uv);
    float p = rowsum16_(h * bl[i * 32 + 16 + n]);
    if (n == 0) ps[wv * 4 + g][i] = fmaf(uv, Dv, p);
  }
  __syncthreads();
  for (int i = tid; i < 16 * CL; i += 256) {
    int row = i >> 6, col = i & 63;
    ybase[(size_t)(d8 * 16 + row) * NL + l0 + col] = ps[row][col];
  }
}

// 6. Fused gate + out-proj. Block = 32-l tile.
__global__ __launch_bounds__(256) void koutg(
    const float* __restrict__ wout, float* __restrict__ ws) {
  int bi = blockIdx.y;
  float* s = ws + (size_t)bi * PER_B;
  int lt = blockIdx.x;
  int l0 = lt * 32;
  int tid = threadIdx.x;
  __shared__ float ot[128][32];
  __shared__ float ot2[64][33];
  for (int i = tid; i < 128 * 32; i += 256) {
    int d = i >> 5, li = i & 31;
    int l = l0 + li;
    float z = s[OXZ + (size_t)(128 + d) * NL + l];
    float v = s[OYF + (size_t)d * NL + l] + s[OYB + (size_t)d * NL + (NL - 1 - l)];
    ot[d][li] = v * siluf_(z);
  }
  __syncthreads();
  {
    int li = tid & 31, cg = tid >> 5;
    float acc[8];
#pragma unroll
    for (int j = 0; j < 8; ++j) acc[j] = 0.f;
    for (int d = 0; d < 128; ++d) {
      float xv = ot[d][li];
#pragma unroll
      for (int j = 0; j < 8; ++j)
        acc[j] = fmaf(wout[(cg * 8 + j) * 128 + d], xv, acc[j]);
    }
#pragma unroll
    for (int j = 0; j < 8; ++j) ot2[cg * 8 + j][li] = acc[j];
  }
  __syncthreads();
  for (int i = tid; i < 32 * 64; i += 256) {
    int li = i >> 6, c = i & 63;
    s[OO2 + (size_t)(l0 + li) * 64 + c] = ot2[c][li];
  }
}

// 7. conv3d partials. Grid = (t, hq, ciq): 256 blocks/slab (4/CU).
__global__ __launch_bounds__(256) void kconv3(
    const float* __restrict__ pw, const float* __restrict__ pb,
    const float* __restrict__ xin, float* __restrict__ ws, int b0) {
  int bi = blockIdx.y, gb = b0 + bi;
  float* s = ws + (size_t)bi * PER_B;
  int t = blockIdx.x >> 4, hq = (blockIdx.x >> 2) & 3, ciq = blockIdx.x & 3;
  int h0 = hq * 4;
  int tid = threadIdx.x;
  int co = tid >> 2, hh = tid & 3;
  int h = h0 + hh;
  const float* xr = s + OO2;
  __shared__ float Xs[16][3][6][18];
  float acc[16];
#pragma unroll
  for (int w = 0; w < 16; ++w) acc[w] = 0.f;

  for (int i = tid; i < 16 * 324; i += 256) {
    int ci = i / 324;
    int rem = i - ci * 324;
    int tt = rem / 108;
    int rem2 = rem - tt * 108;
    int hh2 = rem2 / 18;
    int ww = rem2 - hh2 * 18;
    int ts = t + tt - 1, hs = h0 + hh2 - 1, wv = ww - 1;
    float v = 0.f;
    if (ts >= 0 && ts < 16 && hs >= 0 && hs < 16 && wv >= 0 && wv < 16)
      v = xr[(size_t)(ciq * 16 + ci) * NL + ts * 256 + hs * 16 + wv];
    Xs[ci][tt][hh2][ww] = v;
  }
  __syncthreads();
  const float* wc = pw + (co * 64 + ciq * 16) * 27;
  for (int ci = 0; ci < 16; ++ci) {
#pragma unroll
    for (int kt = 0; kt < 3; ++kt) {
#pragma unroll
      for (int kh = 0; kh < 3; ++kh) {
        const float* wr = wc + ci * 27 + kt * 9 + kh * 3;
        float wv0 = wr[0], wv1 = wr[1], wv2 = wr[2];
        const float* row = &Xs[ci][kt][hh + kh][0];
        float xp = row[0], xc = row[1];
#pragma unroll
        for (int w = 0; w < 16; ++w) {
          float xn = row[w + 2];
          acc[w] = fmaf(wv0, xp, fmaf(wv1, xc, fmaf(wv2, xn, acc[w])));
          xp = xc; xc = xn;
        }
      }
    }
  }
  size_t off = (size_t)co * NL + t * 256 + h * 16;
  if (ciq == 3) {
    float bias = pb[co];
    size_t ibase = (size_t)(gb * 64 + co) * NL + t * 256 + h * 16;
#pragma unroll
    for (int w = 0; w < 16; ++w)
      s[OX4 + off + w] = acc[w] + bias + xin[ibase + w];
  } else {
    size_t dsto = (ciq == 2) ? OX4B : (ciq == 1 ? (OXZ + 262144u) : OXZ);
#pragma unroll
    for (int w = 0; w < 16; ++w)
      s[dsto + off + w] = acc[w];
  }
}

// 8. knorm: LDS-tiled 1x1x1 channel mix over the 4-partial sum + norm_b.
__global__ __launch_bounds__(256) void knorm(
    const float* __restrict__ nw, const float* __restrict__ nb,
    float* __restrict__ out, float* __restrict__ ws, int b0) {
  int bi = blockIdx.y, gb = b0 + bi;
  float* s = ws + (size_t)bi * PER_B;
  int pt = blockIdx.x;
  int p0 = pt * 64;
  int tid = threadIdx.x;
  __shared__ float xs[64][64];
  for (int i = tid; i < 4096; i += 256) {
    int ci = i >> 6, p = i & 63;
    size_t o = (size_t)ci * NL + p0 + p;
    xs[ci][p] = s[OX4 + o] + s[OX4B + o] + s[OXZ + o] + s[OXZ + 262144u + o];
  }
  __syncthreads();
  int co = tid >> 2, pq = tid & 3;
  float acc[16];
#pragma unroll
  for (int j = 0; j < 16; ++j) acc[j] = 0.f;
  for (int ci = 0; ci < 64; ++ci) {
    float wv = nw[co * 64 + ci];
    const float* row = &xs[ci][pq * 16];
#pragma unroll
    for (int j = 0; j < 16; ++j) acc[j] = fmaf(wv, row[j], acc[j]);
  }
  float bias = nb[co];
  float4* dst = (float4*)(out + (size_t)(gb * 64 + co) * NL + p0 + pq * 16);
#pragma unroll
  for (int q = 0; q < 4; ++q)
    dst[q] = make_float4(acc[q * 4] + bias, acc[q * 4 + 1] + bias,
                         acc[q * 4 + 2] + bias, acc[q * 4 + 3] + bias);
}

// ---------------------------------------------------------------------------
extern "C" void kernel_launch(void* const* d_in, const int* in_sizes, int n_in,
                              void* d_out, int out_size, void* d_ws, size_t ws_size,
                              hipStream_t stream) {
  const float* x    = (const float*)d_in[0];
  const float* wip  = (const float*)d_in[1];
  const float* cwf  = (const float*)d_in[2];
  const float* cbf  = (const float*)d_in[3];
  const float* xpf  = (const float*)d_in[4];
  const float* dtwf = (const float*)d_in[5];
  const float* dtbf = (const float*)d_in[6];
  const float* Alf  = (const float*)d_in[7];
  const float* Df   = (const float*)d_in[8];
  const float* cwb  = (const float*)d_in[9];
  const float* cbb  = (const float*)d_in[10];
  const float* xpb  = (const float*)d_in[11];
  const float* dtwb = (const float*)d_in[12];
  const float* dtbb = (const float*)d_in[13];
  const float* Alb  = (const float*)d_in[14];
  const float* Db   = (const float*)d_in[15];
  const float* wout = (const float*)d_in[16];
  const float* pw   = (const float*)d_in[17];
  const float* pb   = (const float*)d_in[18];
  const float* nw   = (const float*)d_in[19];
  const float* nb   = (const float*)d_in[20];

  const size_t PER_B_BYTES = (size_t)PER_B * 4;  // 22,282,240 per batch slab
  int bcnt;
  if (ws_size >= 4 * PER_B_BYTES) bcnt = 4;
  else if (ws_size >= PER_B_BYTES) bcnt = 1;
  else return;
  int passes = 4 / bcnt;

  float* ws = (float*)d_ws;
  for (int p = 0; p < passes; ++p) {
    int b0 = p * bcnt;
    kxz   <<<dim3(256, bcnt), 256, 0, stream>>>(x, wip, ws, b0);
    k2prep<<<dim3(128, bcnt), 256, 0, stream>>>(cwf, cbf, xpf, dtwf, dtbf,
                                                cwb, cbb, xpb, dtwb, dtbb, ws);
    kscanA<<<dim3(1024, bcnt), 256, 0, stream>>>(Alf, Alb, ws);
    kscanB<<<dim3(64, bcnt), 64, 0, stream>>>(ws);
    kscanC<<<dim3(1024, bcnt), 256, 0, stream>>>(Alf, Df, Alb, Db, ws);
    koutg <<<dim3(128, bcnt), 256, 0, stream>>>(wout, ws);
    kconv3<<<dim3(256, bcnt), 256, 0, stream>>>(pw, pb, x, ws, b0);
    knorm <<<dim3(64, bcnt), 256, 0, stream>>>(nw, nb, (float*)d_out, ws, b0);
  }
}

// Round 16
// 326.974 us; speedup vs baseline: 1.5268x; 1.0540x over previous
//
#include <hip/hip_runtime.h>

// ---------------------------------------------------------------------------
// Bidirectional Mamba block, MI355X. Round 15:
//  - kconv3: padded LDS rows (20 floats, 16B-aligned) + float4/float2 row
//    loads into registers -> DS ops/thread 2592 -> 720
//  - kscanA/kscanC: float4 loads of dl/uc (4 scan steps per load pair)
// Everything else identical to passing R14.
// Shapes: B=4, C=64, D=128, L=4096 (l = h*256 + w*16 + t), N=16, R=8.
// ---------------------------------------------------------------------------

#define NL 4096

__device__ __forceinline__ float siluf_(float x) { return x / (1.f + __expf(-x)); }
__device__ __forceinline__ float softplusf_(float x) {
  return (x > 20.f) ? x : log1pf(__expf(x));
}

// Sum over the 16-lane DPP row via rotations 1,2,4,8 (VALU pipe, no DS).
__device__ __forceinline__ float rowsum16_(float p) {
  int q;
  q = __builtin_amdgcn_mov_dpp(__float_as_int(p), 0x121, 0xf, 0xf, false);
  p += __int_as_float(q);
  q = __builtin_amdgcn_mov_dpp(__float_as_int(p), 0x122, 0xf, 0xf, false);
  p += __int_as_float(q);
  q = __builtin_amdgcn_mov_dpp(__float_as_int(p), 0x124, 0xf, 0xf, false);
  p += __int_as_float(q);
  q = __builtin_amdgcn_mov_dpp(__float_as_int(p), 0x128, 0xf, 0xf, false);
  p += __int_as_float(q);
  return p;
}

// Per-b slab offsets (fp32 elements)
#define OXZ  0u          // xz [256][4096]; rows become conv3 partials q0/q1
#define OUCF 1048576u    // ucf  [128][4096]
#define OUCB 1572864u    // ucb  [128][4096]  (flipped coords)
#define ODLF 2424832u    // dlf  [128][4096]
#define ODLB 2949120u    // dlb  [128][4096]  (flipped coords)
#define OYF  3473408u    // yf [128][4096]; first half becomes conv3 partial q2
#define OYB  3997696u    // yb   [128][4096]  (flipped coords)
#define OO   4521984u    // scan scratch: P [262144] S [262144]
#define OO2  5046272u    // bct [2][4096][32] until kscanC; then o2 [4096][64]
#define OX4  5308416u    // conv3 partial q3 (+bias+residual)
#define OX4B 3473408u    // conv3 partial q2 (over dead yf)
#define PER_B 5570560u

#define NCH 64   // scan chunks
#define CL  64   // chunk length

// 1. xz[e,l] = sum_c in_proj_w[e,c] * seq[c,l].
__global__ __launch_bounds__(256) void kxz(
    const float* __restrict__ x, const float* __restrict__ wip,
    float* __restrict__ ws, int b0) {
  int bi = blockIdx.y, gb = b0 + bi;
  float* s = ws + (size_t)bi * PER_B;
  int bid = blockIdx.x;
  int h = bid >> 4, w = bid & 15;
  int tid = threadIdx.x;
  __shared__ float xs[64][16];
  for (int i = tid; i < 1024; i += 256) {
    int c = i >> 4, t = i & 15;
    xs[c][t] = x[(size_t)(gb * 64 + c) * NL + t * 256 + h * 16 + w];
  }
  __syncthreads();
  int e = tid;
  float acc[16];
#pragma unroll
  for (int t = 0; t < 16; ++t) acc[t] = 0.f;
  for (int c = 0; c < 64; ++c) {
    float wv = wip[e * 64 + c];
#pragma unroll
    for (int t = 0; t < 16; ++t) acc[t] = fmaf(wv, xs[c][t], acc[t]);
  }
  float4* dst = (float4*)(s + OXZ + (size_t)e * NL + h * 256 + w * 16);
#pragma unroll
  for (int q = 0; q < 4; ++q)
    dst[q] = make_float4(acc[q * 4], acc[q * 4 + 1], acc[q * 4 + 2], acc[q * 4 + 3]);
}

// 2. Fused prep per (bi, 32-l tile): dwconv+silu, x_dbl (float4), delta, bct.
__global__ __launch_bounds__(256) void k2prep(
    const float* __restrict__ cwf, const float* __restrict__ cbf,
    const float* __restrict__ xpf, const float* __restrict__ dtwf,
    const float* __restrict__ dtbf,
    const float* __restrict__ cwb, const float* __restrict__ cbb,
    const float* __restrict__ xpb, const float* __restrict__ dtwb,
    const float* __restrict__ dtbb,
    float* __restrict__ ws) {
  int bi = blockIdx.y;
  float* s = ws + (size_t)bi * PER_B;
  int lt = blockIdx.x;
  int l0 = lt * 32;
  int l0b = (127 - lt) * 32;
  int tid = threadIdx.x;

  __shared__ float pool[128 * 40];   // X[128][40] during dwconv; xds after
  __shared__ float ucs[2][128][32];
  float (*X)[40] = (float(*)[40])pool;

  for (int i = tid; i < 128 * 38; i += 256) {
    int d = i / 38, j = i - d * 38;
    int l = l0 - 3 + j;
    X[d][j] = (l >= 0 && l < NL) ? s[OXZ + (size_t)d * NL + l] : 0.f;
  }
  __syncthreads();

  for (int i = tid; i < 2 * 128 * 32; i += 256) {
    int br = i >> 12, rem = i & 4095;
    int d = rem >> 5, li = rem & 31;
    float a;
    if (br == 0) {
      a = cbf[d];
#pragma unroll
      for (int k = 0; k < 4; ++k) a = fmaf(cwf[d * 4 + k], X[d][li + k], a);
    } else {
      a = cbb[d];
#pragma unroll
      for (int k = 0; k < 4; ++k) a = fmaf(cwb[d * 4 + k], X[d][37 - li - k], a);
    }
    a = siluf_(a);
    ucs[br][d][li] = a;
    int lg = br ? (l0b + li) : (l0 + li);
    s[(br ? OUCB : OUCF) + (size_t)d * NL + lg] = a;
  }
  __syncthreads();  // X dead; pool becomes xds [2][40][33]

  float* xds = pool;
  for (int i = tid; i < 640; i += 256) {
    int br = i / 320;
    int rem = i - br * 320;
    int e = rem >> 3, liq = rem & 7;
    const float* xp = br ? xpb : xpf;
    float4 acc = make_float4(0.f, 0.f, 0.f, 0.f);
    for (int d = 0; d < 128; ++d) {
      float wv = xp[e * 128 + d];
      const float4 u4 = *(const float4*)&ucs[br][d][liq * 4];
      acc.x = fmaf(wv, u4.x, acc.x);
      acc.y = fmaf(wv, u4.y, acc.y);
      acc.z = fmaf(wv, u4.z, acc.z);
      acc.w = fmaf(wv, u4.w, acc.w);
    }
    float* dst = &xds[(br * 40 + e) * 33 + liq * 4];
    dst[0] = acc.x; dst[1] = acc.y; dst[2] = acc.z; dst[3] = acc.w;
  }
  __syncthreads();

  for (int i = tid; i < 2 * 128 * 32; i += 256) {
    int br = i >> 12, rem = i & 4095;
    int d = rem >> 5, li = rem & 31;
    const float* dtw = br ? dtwb : dtwf;
    float pre = (br ? dtbb : dtbf)[d];
#pragma unroll
    for (int r = 0; r < 8; ++r)
      pre = fmaf(dtw[d * 8 + r], xds[(br * 40 + r) * 33 + li], pre);
    int lg = br ? (l0b + li) : (l0 + li);
    s[(br ? ODLB : ODLF) + (size_t)d * NL + lg] = softplusf_(pre);
  }
  for (int i = tid; i < 2 * 32 * 32; i += 256) {
    int dir = i >> 10;
    int li = (i >> 5) & 31, k = i & 31;
    int lg = dir ? (l0b + li) : (l0 + li);
    s[OO2 + ((size_t)dir * 4096 + lg) * 32 + k] = xds[(dir * 40 + 8 + k) * 33 + li];
  }
}

// 5a. Phase A: 16 d-rows/block; chunk bct in LDS; float4 dl/uc loads.
__global__ __launch_bounds__(256) void kscanA(
    const float* __restrict__ Alf, const float* __restrict__ Alb,
    float* __restrict__ ws) {
  int bi = blockIdx.y;
  float* s = ws + (size_t)bi * PER_B;
  int xid = blockIdx.x;
  int chunk = xid >> 4, dir = (xid >> 3) & 1, d8 = xid & 7;
  int tid = threadIdx.x;
  int wv = tid >> 6, lane = tid & 63;
  int n = lane & 15, g = lane >> 4;
  int d = d8 * 16 + wv * 4 + g;
  int l0 = chunk * CL;
  __shared__ float bl[CL * 32];
  {
    const float* bct = s + OO2 + ((size_t)dir * 4096 + l0) * 32;
    for (int i = tid; i < CL * 32; i += 256) bl[i] = bct[i];
  }
  __syncthreads();
  const float* uc = s + (dir ? OUCB : OUCF) + (size_t)d * NL + l0;
  const float* dl = s + (dir ? ODLB : ODLF) + (size_t)d * NL + l0;
  float A = -__expf((dir ? Alb : Alf)[d * 16 + n]);
  float P = 1.f, S = 0.f;
  for (int i0 = 0; i0 < CL; i0 += 4) {
    float4 d4 = *(const float4*)(dl + i0);
    float4 u4 = *(const float4*)(uc + i0);
    float dv[4] = {d4.x, d4.y, d4.z, d4.w};
    float uv[4] = {u4.x, u4.y, u4.z, u4.w};
#pragma unroll
    for (int j = 0; j < 4; ++j) {
      float dA = __expf(dv[j] * A);
      S = fmaf(dA, S, dv[j] * bl[(i0 + j) * 32 + n] * uv[j]);
      P *= dA;
    }
  }
  size_t cidx = ((size_t)(chunk * 2 + dir) * 128 + d) * 16 + n;
  s[OO + cidx] = P;
  s[OO + 262144u + cidx] = S;
}

// 5b. Phase B: carry combine.
__global__ __launch_bounds__(64) void kscanB(float* __restrict__ ws) {
  int bi = blockIdx.y;
  float* s = ws + (size_t)bi * PER_B;
  int dir = blockIdx.x >> 5, dblk = blockIdx.x & 31;
  int tid = threadIdx.x;
  size_t base = (size_t)dir * 2048 + dblk * 64 + tid;
  float carry = 0.f;
#pragma unroll 4
  for (int c = 0; c < NCH; ++c) {
    size_t idx = (size_t)c * 4096 + base;
    float pv = s[OO + idx], sv = s[OO + 262144u + idx];
    s[OO + 262144u + idx] = carry;
    carry = fmaf(pv, carry, sv);
  }
}

// 5c. Phase C: seeded re-scan; bct in LDS; DPP row-sum; float4 dl/uc loads.
__global__ __launch_bounds__(256) void kscanC(
    const float* __restrict__ Alf, const float* __restrict__ Df,
    const float* __restrict__ Alb, const float* __restrict__ Db,
    float* __restrict__ ws) {
  int bi = blockIdx.y;
  float* s = ws + (size_t)bi * PER_B;
  int xid = blockIdx.x;
  int chunk = xid >> 4, dir = (xid >> 3) & 1, d8 = xid & 7;
  int tid = threadIdx.x;
  int wv = tid >> 6, lane = tid & 63;
  int n = lane & 15, g = lane >> 4;
  int d = d8 * 16 + wv * 4 + g;
  int l0 = chunk * CL;
  __shared__ float bl[CL * 32];
  __shared__ float ps[16][65];
  {
    const float* bct = s + OO2 + ((size_t)dir * 4096 + l0) * 32;
    for (int i = tid; i < CL * 32; i += 256) bl[i] = bct[i];
  }
  __syncthreads();
  const float* uc = s + (dir ? OUCB : OUCF) + (size_t)d * NL + l0;
  const float* dl = s + (dir ? ODLB : ODLF) + (size_t)d * NL + l0;
  float* ybase = s + (dir ? OYB : OYF);
  float A = -__expf((dir ? Alb : Alf)[d * 16 + n]);
  float Dv = (dir ? Db : Df)[d];
  size_t cidx = ((size_t)(chunk * 2 + dir) * 128 + d) * 16 + n;
  float h = s[OO + 262144u + cidx];
  int prow = wv * 4 + g;
  for (int i0 = 0; i0 < CL; i0 += 4) {
    float4 d4 = *(const float4*)(dl + i0);
    float4 u4 = *(const float4*)(uc + i0);
    float dv[4] = {d4.x, d4.y, d4.z, d4.w};
    float uv[4] = {u4.x, u4.y, u4.z, u4.w};
#pragma unroll
    for (int j = 0; j < 4; ++j) {
      int i = i0 + j;
      float dA = __expf(dv[j] * A);
      h = fmaf(dA, h, dv[j] * bl[i * 32 + n] * uv[j]);
      float p = rowsum16_(h * bl[i * 32 + 16 + n]);
      if (n == 0) ps[prow][i] = fmaf(uv[j], Dv, p);
    }
  }
  __syncthreads();
  for (int i = tid; i < 16 * CL; i += 256) {
    int row = i >> 6, col = i & 63;
    ybase[(size_t)(d8 * 16 + row) * NL + l0 + col] = ps[row][col];
  }
}

// 6. Fused gate + out-proj. Block = 32-l tile.
__global__ __launch_bounds__(256) void koutg(
    const float* __restrict__ wout, float* __restrict__ ws) {
  int bi = blockIdx.y;
  float* s = ws + (size_t)bi * PER_B;
  int lt = blockIdx.x;
  int l0 = lt * 32;
  int tid = threadIdx.x;
  __shared__ float ot[128][32];
  __shared__ float ot2[64][33];
  for (int i = tid; i < 128 * 32; i += 256) {
    int d = i >> 5, li = i & 31;
    int l = l0 + li;
    float z = s[OXZ + (size_t)(128 + d) * NL + l];
    float v = s[OYF + (size_t)d * NL + l] + s[OYB + (size_t)d * NL + (NL - 1 - l)];
    ot[d][li] = v * siluf_(z);
  }
  __syncthreads();
  {
    int li = tid & 31, cg = tid >> 5;
    float acc[8];
#pragma unroll
    for (int j = 0; j < 8; ++j) acc[j] = 0.f;
    for (int d = 0; d < 128; ++d) {
      float xv = ot[d][li];
#pragma unroll
      for (int j = 0; j < 8; ++j)
        acc[j] = fmaf(wout[(cg * 8 + j) * 128 + d], xv, acc[j]);
    }
#pragma unroll
    for (int j = 0; j < 8; ++j) ot2[cg * 8 + j][li] = acc[j];
  }
  __syncthreads();
  for (int i = tid; i < 32 * 64; i += 256) {
    int li = i >> 6, c = i & 63;
    s[OO2 + (size_t)(l0 + li) * 64 + c] = ot2[c][li];
  }
}

// 7. conv3d partials. Grid = (t, hq, ciq): 256 blocks/slab (4/CU).
// Rows padded to 20 floats (16B-aligned) -> float4/float2 row loads.
__global__ __launch_bounds__(256) void kconv3(
    const float* __restrict__ pw, const float* __restrict__ pb,
    const float* __restrict__ xin, float* __restrict__ ws, int b0) {
  int bi = blockIdx.y, gb = b0 + bi;
  float* s = ws + (size_t)bi * PER_B;
  int t = blockIdx.x >> 4, hq = (blockIdx.x >> 2) & 3, ciq = blockIdx.x & 3;
  int h0 = hq * 4;
  int tid = threadIdx.x;
  int co = tid >> 2, hh = tid & 3;
  int h = h0 + hh;
  const float* xr = s + OO2;
  __shared__ float Xs[16][3][6][20];  // padded rows: 23 KB, rows 80B-aligned
  float acc[16];
#pragma unroll
  for (int w = 0; w < 16; ++w) acc[w] = 0.f;

  for (int i = tid; i < 16 * 360; i += 256) {
    int ci = i / 360;
    int rem = i - ci * 360;
    int tt = rem / 120;
    int rem2 = rem - tt * 120;
    int hh2 = rem2 / 20;
    int ww = rem2 - hh2 * 20;
    int ts = t + tt - 1, hs = h0 + hh2 - 1, wvv = ww - 1;
    float v = 0.f;
    if (ts >= 0 && ts < 16 && hs >= 0 && hs < 16 && wvv >= 0 && wvv < 16)
      v = xr[(size_t)(ciq * 16 + ci) * NL + ts * 256 + hs * 16 + wvv];
    Xs[ci][tt][hh2][ww] = v;
  }
  __syncthreads();
  const float* wc = pw + (co * 64 + ciq * 16) * 27;
  for (int ci = 0; ci < 16; ++ci) {
#pragma unroll
    for (int kt = 0; kt < 3; ++kt) {
#pragma unroll
      for (int kh = 0; kh < 3; ++kh) {
        const float* wr = wc + ci * 27 + kt * 9 + kh * 3;
        float wv0 = wr[0], wv1 = wr[1], wv2 = wr[2];
        const float* row = &Xs[ci][kt][hh + kh][0];
        float4 r0 = *(const float4*)&row[0];
        float4 r1 = *(const float4*)&row[4];
        float4 r2 = *(const float4*)&row[8];
        float4 r3 = *(const float4*)&row[12];
        float2 r4 = *(const float2*)&row[16];
        float xv[18] = {r0.x, r0.y, r0.z, r0.w, r1.x, r1.y, r1.z, r1.w,
                        r2.x, r2.y, r2.z, r2.w, r3.x, r3.y, r3.z, r3.w,
                        r4.x, r4.y};
#pragma unroll
        for (int w = 0; w < 16; ++w)
          acc[w] = fmaf(wv0, xv[w], fmaf(wv1, xv[w + 1], fmaf(wv2, xv[w + 2], acc[w])));
      }
    }
  }
  size_t off = (size_t)co * NL + t * 256 + h * 16;
  if (ciq == 3) {
    float bias = pb[co];
    size_t ibase = (size_t)(gb * 64 + co) * NL + t * 256 + h * 16;
#pragma unroll
    for (int w = 0; w < 16; ++w)
      s[OX4 + off + w] = acc[w] + bias + xin[ibase + w];
  } else {
    size_t dsto = (ciq == 2) ? OX4B : (ciq == 1 ? (OXZ + 262144u) : OXZ);
#pragma unroll
    for (int w = 0; w < 16; ++w)
      s[dsto + off + w] = acc[w];
  }
}

// 8. knorm: LDS-tiled 1x1x1 channel mix over the 4-partial sum + norm_b.
__global__ __launch_bounds__(256) void knorm(
    const float* __restrict__ nw, const float* __restrict__ nb,
    float* __restrict__ out, float* __restrict__ ws, int b0) {
  int bi = blockIdx.y, gb = b0 + bi;
  float* s = ws + (size_t)bi * PER_B;
  int pt = blockIdx.x;
  int p0 = pt * 64;
  int tid = threadIdx.x;
  __shared__ float xs[64][64];
  for (int i = tid; i < 4096; i += 256) {
    int ci = i >> 6, p = i & 63;
    size_t o = (size_t)ci * NL + p0 + p;
    xs[ci][p] = s[OX4 + o] + s[OX4B + o] + s[OXZ + o] + s[OXZ + 262144u + o];
  }
  __syncthreads();
  int co = tid >> 2, pq = tid & 3;
  float acc[16];
#pragma unroll
  for (int j = 0; j < 16; ++j) acc[j] = 0.f;
  for (int ci = 0; ci < 64; ++ci) {
    float wv = nw[co * 64 + ci];
    const float* row = &xs[ci][pq * 16];
#pragma unroll
    for (int j = 0; j < 16; ++j) acc[j] = fmaf(wv, row[j], acc[j]);
  }
  float bias = nb[co];
  float4* dst = (float4*)(out + (size_t)(gb * 64 + co) * NL + p0 + pq * 16);
#pragma unroll
  for (int q = 0; q < 4; ++q)
    dst[q] = make_float4(acc[q * 4] + bias, acc[q * 4 + 1] + bias,
                         acc[q * 4 + 2] + bias, acc[q * 4 + 3] + bias);
}

// ---------------------------------------------------------------------------
extern "C" void kernel_launch(void* const* d_in, const int* in_sizes, int n_in,
                              void* d_out, int out_size, void* d_ws, size_t ws_size,
                              hipStream_t stream) {
  const float* x    = (const float*)d_in[0];
  const float* wip  = (const float*)d_in[1];
  const float* cwf  = (const float*)d_in[2];
  const float* cbf  = (const float*)d_in[3];
  const float* xpf  = (const float*)d_in[4];
  const float* dtwf = (const float*)d_in[5];
  const float* dtbf = (const float*)d_in[6];
  const float* Alf  = (const float*)d_in[7];
  const float* Df   = (const float*)d_in[8];
  const float* cwb  = (const float*)d_in[9];
  const float* cbb  = (const float*)d_in[10];
  const float* xpb  = (const float*)d_in[11];
  const float* dtwb = (const float*)d_in[12];
  const float* dtbb = (const float*)d_in[13];
  const float* Alb  = (const float*)d_in[14];
  const float* Db   = (const float*)d_in[15];
  const float* wout = (const float*)d_in[16];
  const float* pw   = (const float*)d_in[17];
  const float* pb   = (const float*)d_in[18];
  const float* nw   = (const float*)d_in[19];
  const float* nb   = (const float*)d_in[20];

  const size_t PER_B_BYTES = (size_t)PER_B * 4;  // 22,282,240 per batch slab
  int bcnt;
  if (ws_size >= 4 * PER_B_BYTES) bcnt = 4;
  else if (ws_size >= PER_B_BYTES) bcnt = 1;
  else return;
  int passes = 4 / bcnt;

  float* ws = (float*)d_ws;
  for (int p = 0; p < passes; ++p) {
    int b0 = p * bcnt;
    kxz   <<<dim3(256, bcnt), 256, 0, stream>>>(x, wip, ws, b0);
    k2prep<<<dim3(128, bcnt), 256, 0, stream>>>(cwf, cbf, xpf, dtwf, dtbf,
                                                cwb, cbb, xpb, dtwb, dtbb, ws);
    kscanA<<<dim3(1024, bcnt), 256, 0, stream>>>(Alf, Alb, ws);
    kscanB<<<dim3(64, bcnt), 64, 0, stream>>>(ws);
    kscanC<<<dim3(1024, bcnt), 256, 0, stream>>>(Alf, Df, Alb, Db, ws);
    koutg <<<dim3(128, bcnt), 256, 0, stream>>>(wout, ws);
    kconv3<<<dim3(256, bcnt), 256, 0, stream>>>(pw, pb, x, ws, b0);
    knorm <<<dim3(64, bcnt), 256, 0, stream>>>(nw, nb, (float*)d_out, ws, b0);
  }
}